// Round 10
// baseline (13573.331 us; speedup 1.0000x reference)
//
#include <hip/hip_runtime.h>
#include <hip/hip_bf16.h>
#include <math.h>

// 3-layer masked BiLSTM (B=32,T=1024,D=1024,H=512) + 4 heads.
// Round 10: swapped-operand MFMA recurrence. A = U fragments (M = 4 units x
// 4 gates), B = h (N = batch). All 4 gates of a (b,u) land in one lane's acc
// registers: no sacc LDS transpose, no barrier A, 1 h-store per thread.
// h staging/swizzle/ds_read identical to r9 (pairing perm folded into pack_u).

#define B_ 32
#define T_ 1024
#define H_ 512
#define NG 2048   // 4*H

typedef __attribute__((ext_vector_type(8))) short bf16x8;
typedef __attribute__((ext_vector_type(4))) float f32x4;
typedef unsigned int u32;
typedef unsigned short u16;

__device__ inline u16 f2bf(float f) {          // round-to-nearest-even
    u32 u = __float_as_uint(f);
    return (u16)((u + 0x7fffu + ((u >> 16) & 1u)) >> 16);
}
__device__ inline float bf2f(u16 v) { return __uint_as_float(((u32)v) << 16); }
__device__ inline void gload16(const void* g, void* l) {
    __builtin_amdgcn_global_load_lds(
        (const __attribute__((address_space(1))) u32*)g,
        (__attribute__((address_space(3))) u32*)l, 16, 0, 0);
}
__device__ inline float fsig(float x) { return 1.0f / (1.0f + __expf(-x)); }
__device__ inline float ftanh(float x) { return 1.0f - 2.0f / (__expf(2.0f * x) + 1.0f); }

// ---------------------------------------------------------------- zero
__global__ void zero_mem(float* __restrict__ s, int n) {
    int i = blockIdx.x * 256 + threadIdx.x;
    if (i < n) s[i] = 0.0f;
}

// ---------------------------------------------------------------- fp32 -> bf16
__global__ __launch_bounds__(256) void conv_bf16(const float* __restrict__ src,
                                                 u16* __restrict__ dst) {
    int i = blockIdx.x * 256 + threadIdx.x;
    float4 v = *(const float4*)&src[(size_t)i * 4];
    ushort4 o = { f2bf(v.x), f2bf(v.y), f2bf(v.z), f2bf(v.w) };
    *(ushort4*)&dst[(size_t)i * 4] = o;
}

// ---------------------------------------------------------------- W transpose
// W [1024][2048] fp32  ->  wt [2048][1024] bf16   (6 matrices: l*2+dir)
__global__ __launch_bounds__(256) void transpose_w(const float* __restrict__ Wf,
                                                   const float* __restrict__ Wb,
                                                   u16* __restrict__ wt) {
    int mat = blockIdx.z;
    const float* W = ((mat & 1) ? Wb : Wf) + (size_t)(mat >> 1) * 1024 * NG;
    u16* dst = wt + (size_t)mat * NG * 1024;
    __shared__ float tile[64][65];
    int n0 = blockIdx.x * 64, k0 = blockIdx.y * 64;
    int t = threadIdx.x;
#pragma unroll
    for (int i = 0; i < 16; ++i) {
        int idx = t + i * 256;
        int kk = idx >> 6, nn = idx & 63;
        tile[kk][nn] = W[(size_t)(k0 + kk) * NG + n0 + nn];
    }
    __syncthreads();
#pragma unroll
    for (int i = 0; i < 16; ++i) {
        int idx = t + i * 256;
        int nn = idx >> 6, kk = idx & 63;
        dst[(size_t)(n0 + nn) * 1024 + k0 + kk] = f2bf(tile[kk][nn]);
    }
}

// ---------------------------------------------------------------- U pack (v2)
// U [512][2048] fp32 -> A-side MFMA fragments, bf16. Frag row r = lane&15
// maps to (uu = r>>2, gate = r&3); unit = wg*32 + cp*8 + c2*4 + uu.
// Element j maps to k = ks*32 + (lane>>4)*8 + perm[j], perm = (j&1)*4+(j>>1)
// (compensates the (u, u+4) pairing of the h-word layout).
__global__ __launch_bounds__(256) void pack_u(const float* __restrict__ Uf,
                                              const float* __restrict__ Ub,
                                              u16* __restrict__ upk) {
    int mat = blockIdx.y;               // l*2 + dir
    const float* U = ((mat & 1) ? Ub : Uf) + (size_t)(mat >> 1) * H_ * NG;
    u16* dst = upk + (size_t)mat * 1048576;
    int f = blockIdx.x * 256 + threadIdx.x;
    int lane = f & 63, ks = (f >> 6) & 15, c2 = (f >> 10) & 1;
    int cp = (f >> 11) & 3, wg = f >> 13;
    int r = lane & 15, kb = lane >> 4;
    int col = (r & 3) * H_ + wg * 32 + cp * 8 + c2 * 4 + (r >> 2);
    int kbase = ks * 32 + kb * 8;
    u16 o[8];
#pragma unroll
    for (int j = 0; j < 8; ++j) {
        int k = kbase + (j & 1) * 4 + (j >> 1);
        o[j] = f2bf(U[(size_t)k * NG + col]);
    }
    *(uint4*)(dst + (size_t)f * 8) = *(uint4*)o;
}

// ---------------------------------------------------------------- MFMA GEMM
// Zb[m][u*4+g] (bf16) = sum_k A[row(m)][k] * Bt[n=g*512+u][k] + bias[n]
__global__ __launch_bounds__(256) void gemm_mfma(
    const u16* __restrict__ A, const u16* __restrict__ Bt,
    const float* __restrict__ bias, u16* __restrict__ Zb,
    int t0, int lgC) {
    __shared__ __align__(16) u16 sA[128 * 32];
    __shared__ __align__(16) u16 sB[128 * 32];
    const int tid = threadIdx.x;
    const int m0 = blockIdx.y * 128, n0 = blockIdx.x * 128;
    const int Cmask = (1 << lgC) - 1;

    const int chunk0 = tid, chunk1 = tid + 256;
    const int r0 = chunk0 >> 2, kp0 = (chunk0 & 3) * 8;
    const int r1 = chunk1 >> 2, kp1 = (chunk1 & 3) * 8;
    const int gm0 = m0 + r0, gm1 = m0 + r1;
    const size_t arow0 = ((size_t)(gm0 >> lgC) * T_ + t0 + (gm0 & Cmask)) * 1024;
    const size_t arow1 = ((size_t)(gm1 >> lgC) * T_ + t0 + (gm1 & Cmask)) * 1024;
    const size_t brow0 = (size_t)(n0 + r0) * 1024;
    const size_t brow1 = (size_t)(n0 + r1) * 1024;

    const int lane = tid & 63, wave = tid >> 6;
    const int wr = (wave >> 1) * 64, wc = (wave & 1) * 64;
    const int fr = lane & 15, fk = (lane >> 4) * 8;

    f32x4 acc[4][4] = {};
    for (int kc = 0; kc < 1024; kc += 32) {
        gload16(A + arow0 + kc + kp0, &sA[chunk0 * 8]);
        gload16(A + arow1 + kc + kp1, &sA[chunk1 * 8]);
        gload16(Bt + brow0 + kc + kp0, &sB[chunk0 * 8]);
        gload16(Bt + brow1 + kc + kp1, &sB[chunk1 * 8]);
        __syncthreads();
        bf16x8 af[4], bfr[4];
#pragma unroll
        for (int i = 0; i < 4; ++i)
            af[i] = *(const bf16x8*)&sA[(wr + i * 16 + fr) * 32 + fk];
#pragma unroll
        for (int j = 0; j < 4; ++j)
            bfr[j] = *(const bf16x8*)&sB[(wc + j * 16 + fr) * 32 + fk];
#pragma unroll
        for (int i = 0; i < 4; ++i)
#pragma unroll
            for (int j = 0; j < 4; ++j)
                acc[i][j] = __builtin_amdgcn_mfma_f32_16x16x32_bf16(
                    af[i], bfr[j], acc[i][j], 0, 0, 0);
        __syncthreads();
    }
    float bv[4];
    int un[4], gn[4];
#pragma unroll
    for (int j = 0; j < 4; ++j) {
        int n = n0 + wc + j * 16 + fr;
        bv[j] = bias[n];
        un[j] = n & 511; gn[j] = n >> 9;
    }
#pragma unroll
    for (int i = 0; i < 4; ++i) {
        int mb = m0 + wr + i * 16 + (lane >> 4) * 4;
#pragma unroll
        for (int j = 0; j < 4; ++j) {
#pragma unroll
            for (int r = 0; r < 4; ++r)
                Zb[(size_t)(mb + r) * 2048 + un[j] * 4 + gn[j]] =
                    f2bf(acc[i][j][r] + bv[j]);
        }
    }
}

// ---------------------------------------------------------------- recurrence
// 32 wgs: dir = bx>>4, slice wgs = bx&15 owns u0 = wgs*32 (x4 gates).
// Swapped MFMA: acc0[j] = preact gate j of unit u0+cp*8+fq, batch bt*16+fr;
// acc1 -> unit +4. Gates fully in-lane; 1 packed u32 h-store per thread.
__global__ __launch_bounds__(512, 1) void lstm_chunk(
    const u16* __restrict__ zf, const u16* __restrict__ zb,
    const u16* __restrict__ upk,          // layer base [2 dirs][1048576]
    const int* __restrict__ xmask,
    u32* __restrict__ hbuf32,             // [2 dir][2 parity][8192] u32
    float* __restrict__ cst, float* __restrict__ hst,  // [2*16384]
    u32* __restrict__ flags,              // [2][16] packed (one line/dir)
    u16* __restrict__ hseq,               // [B][T][1024] bf16
    int t0f, int t0b, int C, int sbase) {
    const int bx = blockIdx.x, dir = bx >> 4, wgs = bx & 15, u0 = wgs * 32;
    const u16* z = dir ? zb : zf;         // [B*C][2048] u16, idx u*4+g
    const u16* up = upk + dir * 1048576;
    u32* hb32 = hbuf32 + dir * 16384;
    u32* myflag = flags + dir * 16 + wgs;
    const u32* fbase = flags + dir * 16;
    const int tid = threadIdx.x;
    const int wave = tid >> 6, lane = tid & 63;
    const int cp = wave & 3, bt = wave >> 2, fr = lane & 15, fq = lane >> 4;
    const int row = bt * 16 + fr;                 // batch index (B operand col)
    const int swz = (row & 7) << 4;

    __shared__ __align__(16) u16 sh[16384];       // 32KB staged h (swizzled)

    // U fragments -> registers (stationary across the chunk)
    bf16x8 uf0[16], uf1[16];
#pragma unroll
    for (int ks = 0; ks < 16; ++ks) {
        size_t base0 = (((size_t)(wgs * 4 + cp) * 2) * 16 + ks) * 512 + lane * 8;
        uf0[ks] = *(const bf16x8*)(up + base0);
        uf1[ks] = *(const bf16x8*)(up + base0 + 16 * 512);
    }

    const int ua = u0 + cp * 8 + fq;              // acc0's unit
    const int ub2 = ua + 4;                       // acc1's unit
    const int sidx = (dir * 16 + wgs) * 1024 + tid * 2;
    float ca = cst[sidx], cb = cst[sidx + 1];
    float ha = hst[sidx], hb2 = hst[sidx + 1];
    const size_t hsA = (size_t)row * T_ * 1024 + dir * 512 + ua;
    const int hword = row * 256 + wgs * 16 + cp * 4 + fq;

    // prologue: stage parity-0 h into LDS (agent atomic loads + swizzled write)
    {
        u32 tmp[16];
#pragma unroll
        for (int k = 0; k < 16; ++k)
            tmp[k] = __hip_atomic_load(hb32 + k * 512 + tid, __ATOMIC_RELAXED,
                                       __HIP_MEMORY_SCOPE_AGENT);
#pragma unroll
        for (int k = 0; k < 16; ++k) {
            int idx = k * 512 + tid;
            int sb = (idx * 4) ^ (((idx >> 8) & 7) << 4);
            *(u32*)((char*)sh + sb) = tmp[k];
        }
    }
    // z/mask for step 0
    ushort4 zA, zB; int mc;
    {
        int tc = dir ? (C - 1) : 0;
        int t = dir ? (t0b + C - 1) : t0f;
        const u16* zr = z + ((size_t)(row * C + tc)) * 2048;
        zA = *(const ushort4*)(zr + ua * 4);
        zB = *(const ushort4*)(zr + ub2 * 4);
        mc = xmask[row * T_ + t];
    }
    __syncthreads();

    u16 h16a = 0, h16b = 0;
    for (int st = 0; st < C; ++st) {
        const int t = dir ? (t0b + C - 1 - st) : (t0f + st);
        u32* nx32 = hb32 + (((st & 1) ^ 1) ? 8192 : 0);

        // MFMA: A = U frags (regs), B = h from LDS (swizzled), over K=512
        f32x4 acc0 = {0, 0, 0, 0}, acc1 = {0, 0, 0, 0};
#pragma unroll
        for (int ks = 0; ks < 16; ++ks) {
            int abyte = (row * 1024 + ks * 64 + fq * 16) ^ swz;
            bf16x8 b = *(const bf16x8*)((const char*)sh + abyte);
            acc0 = __builtin_amdgcn_mfma_f32_16x16x32_bf16(uf0[ks], b, acc0, 0, 0, 0);
            acc1 = __builtin_amdgcn_mfma_f32_16x16x32_bf16(uf1[ks], b, acc1, 0, 0, 0);
        }
        // gates fully in-lane (acc0[j] = gate j of (row, ua); acc1 -> ub2)
        {
            float i0 = fsig(bf2f(zA.x) + acc0[0]);
            float f0 = fsig(bf2f(zA.y) + acc0[1]);
            float g0 = ftanh(bf2f(zA.z) + acc0[2]);
            float o0 = fsig(bf2f(zA.w) + acc0[3]);
            if (mc != 1) { ca = f0 * ca + i0 * g0; ha = o0 * ftanh(ca); }
            float i1 = fsig(bf2f(zB.x) + acc1[0]);
            float f1 = fsig(bf2f(zB.y) + acc1[1]);
            float g1 = ftanh(bf2f(zB.z) + acc1[2]);
            float o1 = fsig(bf2f(zB.w) + acc1[3]);
            if (mc != 1) { cb = f1 * cb + i1 * g1; hb2 = o1 * ftanh(cb); }
            h16a = f2bf(ha); h16b = f2bf(hb2);
            u32 pk = (u32)h16a | ((u32)h16b << 16);
            __hip_atomic_store(nx32 + hword, pk,
                               __ATOMIC_RELAXED, __HIP_MEMORY_SCOPE_AGENT);
        }
        __syncthreads();   // B: implicit vmcnt(0) drains every thread's store
        const u32 tgt = (u32)(sbase + st + 1);
        if (tid == 0)
            __hip_atomic_store(myflag, tgt, __ATOMIC_RELAXED,
                               __HIP_MEMORY_SCOPE_AGENT);
        // hseq stores: fire-and-forget, hidden under poll+stage
        hseq[hsA + (size_t)t * 1024] = h16a;
        hseq[hsA + 4 + (size_t)t * 1024] = h16b;
        // prefetch next-step z/mask (flies during the poll)
        ushort4 znA, znB; int mn;
        {
            int stn = (st + 1 < C) ? st + 1 : st;
            int tcn = dir ? (C - 1 - stn) : stn;
            int tn = dir ? (t0b + tcn) : (t0f + tcn);
            const u16* zr = z + ((size_t)(row * C + tcn)) * 2048;
            znA = *(const ushort4*)(zr + ua * 4);
            znB = *(const ushort4*)(zr + ub2 * 4);
            mn = xmask[row * T_ + tn];
        }
        // per-wave poll of the packed flag line (lanes<16 issue loads)
        {
            u32 v = 0xffffffffu;
            if (lane < 16)
                v = __hip_atomic_load(fbase + lane, __ATOMIC_RELAXED,
                                      __HIP_MEMORY_SCOPE_AGENT);
            while (!__all(v >= tgt)) {
                if (lane < 16)
                    v = __hip_atomic_load(fbase + lane, __ATOMIC_RELAXED,
                                          __HIP_MEMORY_SCOPE_AGENT);
            }
        }
        // stage next-parity h into LDS (coalesced agent loads, swizzled write)
        if (st + 1 < C) {
            const u32* src = hb32 + (((st + 1) & 1) ? 8192 : 0);
            u32 tmp[16];
#pragma unroll
            for (int k = 0; k < 16; ++k)
                tmp[k] = __hip_atomic_load(src + k * 512 + tid, __ATOMIC_RELAXED,
                                           __HIP_MEMORY_SCOPE_AGENT);
#pragma unroll
            for (int k = 0; k < 16; ++k) {
                int idx = k * 512 + tid;
                int sb = (idx * 4) ^ (((idx >> 8) & 7) << 4);
                *(u32*)((char*)sh + sb) = tmp[k];
            }
        }
        zA = znA; zB = znB; mc = mn;
        __syncthreads();                               // C: sh staged by all
    }
    cst[sidx] = ca; cst[sidx + 1] = cb;
    hst[sidx] = ha; hst[sidx + 1] = hb2;
}

// ---------------------------------------------------------------- heads
__global__ __launch_bounds__(256) void heads_kernel(
    const u16* __restrict__ xin,
    const float* __restrict__ Wp, const float* __restrict__ bp,
    const float* __restrict__ Wbu, const float* __restrict__ bbu,
    const float* __restrict__ Wss3, const float* __restrict__ bss3,
    const float* __restrict__ Wss8, const float* __restrict__ bss8,
    float* __restrict__ out) {
    const int r = blockIdx.x * 4 + (threadIdx.x >> 6);
    const int lane = threadIdx.x & 63;
    const u16* xr = xin + (size_t)r * 1024 + lane * 16;
    uint4 q0 = *(const uint4*)xr;
    uint4 q1 = *(const uint4*)(xr + 8);
    float xv[16];
    u32 qs[8] = { q0.x, q0.y, q0.z, q0.w, q1.x, q1.y, q1.z, q1.w };
#pragma unroll
    for (int i = 0; i < 8; ++i) {
        xv[i * 2]     = fmaxf(__uint_as_float((qs[i] & 0xffffu) << 16), 0.0f);
        xv[i * 2 + 1] = fmaxf(__uint_as_float(qs[i] & 0xffff0000u), 0.0f);
    }
    float acc[15] = {};
    const int k0 = lane * 16;
#pragma unroll
    for (int kk = 0; kk < 16; kk++) {
        float xk = xv[kk];
        int k = k0 + kk;
        acc[0] += xk * Wp[k * 2];      acc[1] += xk * Wp[k * 2 + 1];
        acc[2] += xk * Wbu[k * 2];     acc[3] += xk * Wbu[k * 2 + 1];
        acc[4] += xk * Wss3[k * 3];    acc[5] += xk * Wss3[k * 3 + 1];
        acc[6] += xk * Wss3[k * 3 + 2];
#pragma unroll
        for (int o = 0; o < 8; o++) acc[7 + o] += xk * Wss8[k * 8 + o];
    }
#pragma unroll
    for (int o = 0; o < 15; o++) {
#pragma unroll
        for (int off = 32; off; off >>= 1) acc[o] += __shfl_xor(acc[o], off, 64);
    }
    if (lane == 0) {
        float a0 = acc[0] + bp[0], a1 = acc[1] + bp[1];
        float mx = fmaxf(a0, a1);
        float e0 = expf(a0 - mx), e1 = expf(a1 - mx);
        float ssum = e0 + e1;
        out[(size_t)r * 2] = e0 / ssum;
        out[(size_t)r * 2 + 1] = e1 / ssum;
        float* ob = out + 65536;
        ob[r * 2] = acc[2] + bbu[0]; ob[r * 2 + 1] = acc[3] + bbu[1];
        float* o3 = out + 131072;
        o3[r * 3 + 0] = acc[4] + bss3[0];
        o3[r * 3 + 1] = acc[5] + bss3[1];
        o3[r * 3 + 2] = acc[6] + bss3[2];
        float* o8 = out + 229376;
#pragma unroll
        for (int o = 0; o < 8; o++) o8[r * 8 + o] = acc[7 + o] + bss8[o];
    }
}

// ---------------------------------------------------------------- launch
extern "C" void kernel_launch(void* const* d_in, const int* in_sizes, int n_in,
                              void* d_out, int out_size, void* d_ws, size_t ws_size,
                              hipStream_t stream) {
    const float* x = (const float*)d_in[0];
    const int* xmask = (const int*)d_in[1];
    const float* Wf = (const float*)d_in[2];
    const float* Uf = (const float*)d_in[3];
    const float* bfp = (const float*)d_in[4];
    const float* Wb = (const float*)d_in[5];
    const float* Ub = (const float*)d_in[6];
    const float* bbp = (const float*)d_in[7];
    const float* Wp = (const float*)d_in[8];
    const float* bp = (const float*)d_in[9];
    const float* Wbu = (const float*)d_in[10];
    const float* bbu = (const float*)d_in[11];
    const float* Wss3 = (const float*)d_in[12];
    const float* bss3 = (const float*)d_in[13];
    const float* Wss8 = (const float*)d_in[14];
    const float* bss8 = (const float*)d_in[15];

    char* wsb = (char*)d_ws;
    u16* actA = (u16*)wsb;                               // 64 MB
    u16* actB = (u16*)(wsb + (64ull << 20));             // 64 MB
    u16* wt   = (u16*)(wsb + (128ull << 20));            // 24 MB
    u16* upk  = (u16*)(wsb + (152ull << 20));            // 12 MB
    char* stb = wsb + (164ull << 20);                    // states
    u32* hbuf32 = (u32*)stb;                             // 131072 B
    float* cst = (float*)(stb + 131072);                 // 131072 B
    float* hst = (float*)(stb + 262144);                 // 131072 B
    u32* flags = (u32*)(stb + 393216);                   // 128 B packed
    const int stateFloats = (393216 + 128) / 4;

    size_t fixedB = 165ull << 20;
    int C = 1024;
    while (C > 128 && fixedB + 262144ull * C > ws_size) C >>= 1;
    int lgC = 31 - __builtin_clz((unsigned)C);
    u16* zf = (u16*)(wsb + fixedB);
    u16* zb = zf + (size_t)B_ * C * 2048;

    conv_bf16<<<dim3(8388608 / 256), 256, 0, stream>>>(x, actA);
    transpose_w<<<dim3(32, 16, 6), 256, 0, stream>>>(Wf, Wb, wt);
    pack_u<<<dim3(512, 6), 256, 0, stream>>>(Uf, Ub, upk);

    const u16* cur = actA;
    for (int l = 0; l < 3; l++) {
        u16* dst = (l & 1) ? actA : actB;
        zero_mem<<<dim3((stateFloats + 255) / 256), 256, 0, stream>>>(
            (float*)stb, stateFloats);
        u16* wtf = wt + (size_t)(l * 2 + 0) * NG * 1024;
        u16* wtb = wt + (size_t)(l * 2 + 1) * NG * 1024;
        const u16* upkl = upk + (size_t)l * 2 * 1048576;
        const float* bfl = bfp + l * NG;
        const float* bbl = bbp + l * NG;
        for (int c0 = 0; c0 < T_; c0 += C) {
            int t0f = c0;
            int t0b = T_ - c0 - C;
            dim3 ggrid(NG / 128, (B_ * C) / 128);
            gemm_mfma<<<ggrid, 256, 0, stream>>>(cur, wtf, bfl, zf, t0f, lgC);
            gemm_mfma<<<ggrid, 256, 0, stream>>>(cur, wtb, bbl, zb, t0b, lgC);

            const u16* a_zf = zf; const u16* a_zb = zb;
            const u16* a_up = upkl; const int* a_xm = xmask;
            u32* a_hb = hbuf32; float* a_cs = cst; float* a_hs = hst;
            u32* a_fl = flags; u16* a_hseq = dst;
            int a_t0f = t0f, a_t0b = t0b, a_C = C, a_sb = c0;
            void* kargs[] = { &a_zf, &a_zb, &a_up, &a_xm, &a_hb, &a_cs, &a_hs,
                              &a_fl, &a_hseq, &a_t0f, &a_t0b, &a_C, &a_sb };
            hipLaunchCooperativeKernel((void*)lstm_chunk, dim3(32), dim3(512),
                                       kargs, 0, stream);
        }
        cur = dst;
    }
    heads_kernel<<<dim3(B_ * T_ / 4), 256, 0, stream>>>(
        cur, Wp, bp, Wbu, bbu, Wss3, bss3, Wss8, bss8, (float*)d_out);
}

// Round 12
// 12203.024 us; speedup vs baseline: 1.1123x; 1.1123x over previous
//
#include <hip/hip_runtime.h>
#include <hip/hip_bf16.h>
#include <math.h>

// 3-layer masked BiLSTM (B=32,T=1024,D=1024,H=512) + 4 heads.
// Round 12: r11 (fused z-GEMM + recurrence) with the producer stride bug
// fixed: 112 wgs per dir stride by 112 (r11's 224 left half the tiles
// unproduced -> consumer counters never hit 512 -> hang).

#define B_ 32
#define T_ 1024
#define H_ 512
#define NG 2048   // 4*H

typedef __attribute__((ext_vector_type(8))) short bf16x8;
typedef __attribute__((ext_vector_type(4))) float f32x4;
typedef unsigned int u32;
typedef unsigned long long u64;
typedef unsigned short u16;

__device__ inline u16 f2bf(float f) {          // round-to-nearest-even
    u32 u = __float_as_uint(f);
    return (u16)((u + 0x7fffu + ((u >> 16) & 1u)) >> 16);
}
__device__ inline float bf2f(u16 v) { return __uint_as_float(((u32)v) << 16); }
__device__ inline void gload16(const void* g, void* l) {
    __builtin_amdgcn_global_load_lds(
        (const __attribute__((address_space(1))) u32*)g,
        (__attribute__((address_space(3))) u32*)l, 16, 0, 0);
}
__device__ inline float fsig(float x) { return 1.0f / (1.0f + __expf(-x)); }
__device__ inline float ftanh(float x) { return 1.0f - 2.0f / (__expf(2.0f * x) + 1.0f); }

// ---------------------------------------------------------------- zero
__global__ void zero_mem(float* __restrict__ s, int n) {
    int i = blockIdx.x * 256 + threadIdx.x;
    if (i < n) s[i] = 0.0f;
}

// ---------------------------------------------------------------- fp32 -> bf16
__global__ __launch_bounds__(256) void conv_bf16(const float* __restrict__ src,
                                                 u16* __restrict__ dst) {
    int i = blockIdx.x * 256 + threadIdx.x;
    float4 v = *(const float4*)&src[(size_t)i * 4];
    ushort4 o = { f2bf(v.x), f2bf(v.y), f2bf(v.z), f2bf(v.w) };
    *(ushort4*)&dst[(size_t)i * 4] = o;
}

// ---------------------------------------------------------------- W transpose
// W [1024][2048] fp32  ->  wt [2048][1024] bf16   (6 matrices: l*2+dir)
__global__ __launch_bounds__(256) void transpose_w(const float* __restrict__ Wf,
                                                   const float* __restrict__ Wb,
                                                   u16* __restrict__ wt) {
    int mat = blockIdx.z;
    const float* W = ((mat & 1) ? Wb : Wf) + (size_t)(mat >> 1) * 1024 * NG;
    u16* dst = wt + (size_t)mat * NG * 1024;
    __shared__ float tile[64][65];
    int n0 = blockIdx.x * 64, k0 = blockIdx.y * 64;
    int t = threadIdx.x;
#pragma unroll
    for (int i = 0; i < 16; ++i) {
        int idx = t + i * 256;
        int kk = idx >> 6, nn = idx & 63;
        tile[kk][nn] = W[(size_t)(k0 + kk) * NG + n0 + nn];
    }
    __syncthreads();
#pragma unroll
    for (int i = 0; i < 16; ++i) {
        int idx = t + i * 256;
        int nn = idx >> 6, kk = idx & 63;
        dst[(size_t)(n0 + nn) * 1024 + k0 + kk] = f2bf(tile[kk][nn]);
    }
}

// ---------------------------------------------------------------- U pack (r9)
// U [512][2048] fp32 -> MFMA B-fragment order, bf16.
__global__ __launch_bounds__(256) void pack_u(const float* __restrict__ Uf,
                                              const float* __restrict__ Ub,
                                              u16* __restrict__ upk) {
    int mat = blockIdx.y;               // l*2 + dir
    const float* U = ((mat & 1) ? Ub : Uf) + (size_t)(mat >> 1) * H_ * NG;
    u16* dst = upk + (size_t)mat * 1048576;
    int f = blockIdx.x * 256 + threadIdx.x;
    int lane = f & 63, ks = (f >> 6) & 15, c2 = (f >> 10) & 1;
    int cp = (f >> 11) & 3, wg = f >> 13;
    int col = cp * H_ + wg * 32 + c2 * 16 + (lane & 15);
    int krow = ks * 32 + (lane >> 4) * 8;
    u16 o[8];
#pragma unroll
    for (int j = 0; j < 8; ++j) o[j] = f2bf(U[(size_t)(krow + j) * NG + col]);
    *(uint4*)(dst + (size_t)f * 8) = *(uint4*)o;
}

// ---------------------------------------------------------------- fused layer
// 256 wgs x 512 threads, cooperative. wgs 0-31: recurrence (r9 body).
// wgs 32-255: z-GEMM, 112 per dir, tiles in consumption order.
__global__ __launch_bounds__(512, 1) void fused_layer(
    const u16* __restrict__ act,          // [B*T][1024] bf16
    const u16* __restrict__ wtf, const u16* __restrict__ wtb,  // [2048][1024]
    const float* __restrict__ bfl, const float* __restrict__ bbl,
    u16* __restrict__ zf, u16* __restrict__ zb,   // [B*T][2048] gate-ilv bf16
    const u16* __restrict__ upk,          // [2 dirs][1048576]
    const int* __restrict__ xmask,
    u32* __restrict__ hbuf32,             // [2 dir][2 parity][8192] u32
    float* __restrict__ cst, float* __restrict__ hst,  // [2*16384]
    u32* __restrict__ flags,              // [2][16] packed
    u32* __restrict__ cnt,                // [2][8] t-block tile counters
    u16* __restrict__ hseq) {             // [B][T][1024] bf16
    const int bx = blockIdx.x;
    const int tid = threadIdx.x;
    const int wave = tid >> 6, lane = tid & 63;
    const int fr = lane & 15, fq = lane >> 4;

    __shared__ __align__(16) u16 sh[16384];       // 32KB (recur: h / gemm: A+B)
    __shared__ float sacc[32 * 132];              // recur gate preacts

    if (bx >= 32) {
        // ---------------- GEMM producer ----------------
        const int g = bx - 32;
        const int dir = (g >= 112) ? 1 : 0;
        const int local = dir ? g - 112 : g;
        const u16* Bt = dir ? wtb : wtf;
        const float* bias = dir ? bbl : bfl;
        u16* Zb = dir ? zb : zf;
        u32* mycnt = cnt + dir * 8;
        u16* sA = sh;                 // [128][32]
        u16* sB = sh + 4096;          // [128][32]
        const int r = tid >> 2, kp = (tid & 3) * 8;
        const int wr = (wave & 1) * 64, wc = (wave >> 1) * 32;
        for (int i = local; i < 4096; i += 112) {   // FIX: stride = wgs/dir
            int tb_ord = i >> 9, within = i & 511;
            int b = within >> 4, nt = within & 15;
            int tb = dir ? 7 - tb_ord : tb_ord;
            int m0 = b * 1024 + tb * 128;
            int n0 = nt * 128;
            const size_t arow = (size_t)(m0 + r) * 1024;   // act row == m
            const size_t brow = (size_t)(n0 + r) * 1024;
            f32x4 acc[4][2] = {};
            for (int kc = 0; kc < 1024; kc += 32) {
                gload16(act + arow + kc + kp, sA + tid * 8);
                gload16(Bt + brow + kc + kp, sB + tid * 8);
                __syncthreads();
                bf16x8 af[4], bfr[2];
                const int fk = fq * 8;
#pragma unroll
                for (int ii = 0; ii < 4; ++ii)
                    af[ii] = *(const bf16x8*)&sA[(wr + ii * 16 + fr) * 32 + fk];
#pragma unroll
                for (int j = 0; j < 2; ++j)
                    bfr[j] = *(const bf16x8*)&sB[(wc + j * 16 + fr) * 32 + fk];
#pragma unroll
                for (int ii = 0; ii < 4; ++ii)
#pragma unroll
                    for (int j = 0; j < 2; ++j)
                        acc[ii][j] = __builtin_amdgcn_mfma_f32_16x16x32_bf16(
                            af[ii], bfr[j], acc[ii][j], 0, 0, 0);
                __syncthreads();
            }
            float bv[2]; int un[2], gn[2];
#pragma unroll
            for (int j = 0; j < 2; ++j) {
                int n = n0 + wc + j * 16 + fr;
                bv[j] = bias[n];
                un[j] = n & 511; gn[j] = n >> 9;
            }
#pragma unroll
            for (int ii = 0; ii < 4; ++ii) {
                int mb = m0 + wr + ii * 16 + fq * 4;
#pragma unroll
                for (int j = 0; j < 2; ++j)
#pragma unroll
                    for (int rr = 0; rr < 4; ++rr)
                        Zb[(size_t)(mb + rr) * 2048 + un[j] * 4 + gn[j]] =
                            f2bf(acc[ii][j][rr] + bv[j]);
            }
            __syncthreads();          // all threads' stores complete (in L2)
            if (tid == 0) {
                __threadfence();      // wbl2: push tile to coherence point
                __hip_atomic_fetch_add(mycnt + tb, 1u, __ATOMIC_RELAXED,
                                       __HIP_MEMORY_SCOPE_AGENT);
            }
        }
        return;
    }

    // ---------------- recurrence (r9 body + z atomic u64 + tb gating) -------
    const int dir = bx >> 4, wgs = bx & 15, u0 = wgs * 32;
    const u64* z64 = (const u64*)(dir ? zb : zf);   // u64 idx = row*512 + u
    const u16* up = upk + dir * 1048576;
    u32* hb32 = hbuf32 + dir * 16384;
    u32* myflag = flags + dir * 16 + wgs;
    const u32* fbase = flags + dir * 16;
    const u32* ctb = cnt + dir * 8;
    const int cp = wave & 3, bt = wave >> 2;
    const int row = bt * 16 + fr;                 // batch index for B frags
    const int swz = (row & 7) << 4;

    // U fragments -> registers (stationary across the layer)
    bf16x8 uf0[16], uf1[16];
#pragma unroll
    for (int ks = 0; ks < 16; ++ks) {
        size_t base0 = (((size_t)(wgs * 4 + cp) * 2) * 16 + ks) * 512 + lane * 8;
        uf0[ks] = *(const bf16x8*)(up + base0);
        uf1[ks] = *(const bf16x8*)(up + base0 + 16 * 512);
    }

    const int b0p = tid >> 5, ul = tid & 31, b1p = b0p + 16, ug = u0 + ul;
    const int sidx = (dir * 16 + wgs) * 1024 + tid * 2;
    float c0r = cst[sidx], c1r = cst[sidx + 1];
    float h0r = hst[sidx], h1r = hst[sidx + 1];
    const size_t hs0 = (size_t)b0p * T_ * 1024 + dir * 512 + ug;
    const size_t hs1 = (size_t)b1p * T_ * 1024 + dir * 512 + ug;

    int haveb = -1;
    auto wait_tb = [&](int tb) {
        if (tb == haveb) return;
        const u32* cpp = ctb + tb;
        u32 v = 512;
        if (lane == 0) v = __hip_atomic_load(cpp, __ATOMIC_RELAXED,
                                             __HIP_MEMORY_SCOPE_AGENT);
        while (!__all(v >= 512)) {
            if (lane == 0) v = __hip_atomic_load(cpp, __ATOMIC_RELAXED,
                                                 __HIP_MEMORY_SCOPE_AGENT);
        }
        haveb = tb;
    };

    // prologue: stage parity-0 h into LDS (agent atomic loads + swizzled write)
    {
        u32 tmp[16];
#pragma unroll
        for (int k = 0; k < 16; ++k)
            tmp[k] = __hip_atomic_load(hb32 + k * 512 + tid, __ATOMIC_RELAXED,
                                       __HIP_MEMORY_SCOPE_AGENT);
#pragma unroll
        for (int k = 0; k < 16; ++k) {
            int idx = k * 512 + tid;
            int sb = (idx * 4) ^ (((idx >> 8) & 7) << 4);
            *(u32*)((char*)sh + sb) = tmp[k];
        }
    }
    // z/mask for step 0 (gated on its t-block)
    u64 za0, za1; int mc0, mc1;
    {
        int tc = dir ? (T_ - 1) : 0;
        wait_tb(tc >> 7);
        za0 = __hip_atomic_load(z64 + (size_t)(b0p * T_ + tc) * 512 + ug,
                                __ATOMIC_RELAXED, __HIP_MEMORY_SCOPE_AGENT);
        za1 = __hip_atomic_load(z64 + (size_t)(b1p * T_ + tc) * 512 + ug,
                                __ATOMIC_RELAXED, __HIP_MEMORY_SCOPE_AGENT);
        mc0 = xmask[b0p * T_ + tc]; mc1 = xmask[b1p * T_ + tc];
    }
    __syncthreads();

    u16 hb0s = 0, hb1s = 0;
    for (int st = 0; st < T_; ++st) {
        const int t = dir ? (T_ - 1 - st) : st;
        u32* nx32 = hb32 + (((st & 1) ^ 1) ? 8192 : 0);

        // MFMA from LDS (swizzled) x register U, over K=512
        f32x4 acc0 = {0, 0, 0, 0}, acc1 = {0, 0, 0, 0};
#pragma unroll
        for (int ks = 0; ks < 16; ++ks) {
            int abyte = (row * 1024 + ks * 64 + fq * 16) ^ swz;
            bf16x8 a = *(const bf16x8*)((const char*)sh + abyte);
            acc0 = __builtin_amdgcn_mfma_f32_16x16x32_bf16(a, uf0[ks], acc0, 0, 0, 0);
            acc1 = __builtin_amdgcn_mfma_f32_16x16x32_bf16(a, uf1[ks], acc1, 0, 0, 0);
        }
#pragma unroll
        for (int j = 0; j < 4; ++j) {
            int b = bt * 16 + fq * 4 + j;
            sacc[b * 132 + cp * 32 + fr] = acc0[j];
            sacc[b * 132 + cp * 32 + 16 + fr] = acc1[j];
        }
        __syncthreads();                               // A: sacc visible
        // pointwise gates + state update + coherent h stores
        {
            const float* s0 = sacc + b0p * 132;
            const float* s1 = sacc + b1p * 132;
            float i0 = fsig(bf2f((u16)za0) + s0[ul]);
            float f0 = fsig(bf2f((u16)(za0 >> 16)) + s0[32 + ul]);
            float g0 = ftanh(bf2f((u16)(za0 >> 32)) + s0[64 + ul]);
            float o0 = fsig(bf2f((u16)(za0 >> 48)) + s0[96 + ul]);
            if (mc0 != 1) { c0r = f0 * c0r + i0 * g0; h0r = o0 * ftanh(c0r); }
            float i1 = fsig(bf2f((u16)za1) + s1[ul]);
            float f1 = fsig(bf2f((u16)(za1 >> 16)) + s1[32 + ul]);
            float g1 = ftanh(bf2f((u16)(za1 >> 32)) + s1[64 + ul]);
            float o1 = fsig(bf2f((u16)(za1 >> 48)) + s1[96 + ul]);
            if (mc1 != 1) { c1r = f1 * c1r + i1 * g1; h1r = o1 * ftanh(c1r); }
            hb0s = f2bf(h0r); hb1s = f2bf(h1r);
            u32 nb0 = __shfl_xor((u32)hb0s, 1, 64);
            u32 nb1 = __shfl_xor((u32)hb1s, 1, 64);
            if ((ul & 1) == 0) {
                u32 pk0 = (u32)hb0s | (nb0 << 16);
                u32 pk1 = (u32)hb1s | (nb1 << 16);
                __hip_atomic_store(nx32 + b0p * 256 + (ug >> 1), pk0,
                                   __ATOMIC_RELAXED, __HIP_MEMORY_SCOPE_AGENT);
                __hip_atomic_store(nx32 + b1p * 256 + (ug >> 1), pk1,
                                   __ATOMIC_RELAXED, __HIP_MEMORY_SCOPE_AGENT);
            }
        }
        __syncthreads();   // B: implicit vmcnt(0) drains every thread's stores
        const u32 tgt = (u32)(st + 1);
        if (tid == 0)
            __hip_atomic_store(myflag, tgt, __ATOMIC_RELAXED,
                               __HIP_MEMORY_SCOPE_AGENT);
        // hseq stores: fire-and-forget, hidden under poll+stage
        hseq[hs0 + (size_t)t * 1024] = hb0s;
        hseq[hs1 + (size_t)t * 1024] = hb1s;
        // prefetch next-step z/mask (flies during the poll)
        u64 zn0 = 0, zn1 = 0; int mn0 = 0, mn1 = 0;
        {
            int stn = (st + 1 < T_) ? st + 1 : st;
            int tcn = dir ? (T_ - 1 - stn) : stn;
            wait_tb(tcn >> 7);
            zn0 = __hip_atomic_load(z64 + (size_t)(b0p * T_ + tcn) * 512 + ug,
                                    __ATOMIC_RELAXED, __HIP_MEMORY_SCOPE_AGENT);
            zn1 = __hip_atomic_load(z64 + (size_t)(b1p * T_ + tcn) * 512 + ug,
                                    __ATOMIC_RELAXED, __HIP_MEMORY_SCOPE_AGENT);
            mn0 = xmask[b0p * T_ + tcn]; mn1 = xmask[b1p * T_ + tcn];
        }
        // per-wave poll of the packed flag line (lanes<16 issue loads)
        {
            u32 v = 0xffffffffu;
            if (lane < 16)
                v = __hip_atomic_load(fbase + lane, __ATOMIC_RELAXED,
                                      __HIP_MEMORY_SCOPE_AGENT);
            while (!__all(v >= tgt)) {
                if (lane < 16)
                    v = __hip_atomic_load(fbase + lane, __ATOMIC_RELAXED,
                                          __HIP_MEMORY_SCOPE_AGENT);
            }
        }
        // stage next-parity h into LDS (coalesced agent loads, swizzled write)
        if (st + 1 < T_) {
            const u32* src = hb32 + (((st + 1) & 1) ? 8192 : 0);
            u32 tmp[16];
#pragma unroll
            for (int k = 0; k < 16; ++k)
                tmp[k] = __hip_atomic_load(src + k * 512 + tid, __ATOMIC_RELAXED,
                                           __HIP_MEMORY_SCOPE_AGENT);
#pragma unroll
            for (int k = 0; k < 16; ++k) {
                int idx = k * 512 + tid;
                int sb = (idx * 4) ^ (((idx >> 8) & 7) << 4);
                *(u32*)((char*)sh + sb) = tmp[k];
            }
        }
        za0 = zn0; za1 = zn1; mc0 = mn0; mc1 = mn1;
        __syncthreads();                               // C: sh staged by all
    }
    cst[sidx] = c0r; cst[sidx + 1] = c1r;
    hst[sidx] = h0r; hst[sidx + 1] = h1r;
}

// ---------------------------------------------------------------- heads
__global__ __launch_bounds__(256) void heads_kernel(
    const u16* __restrict__ xin,
    const float* __restrict__ Wp, const float* __restrict__ bp,
    const float* __restrict__ Wbu, const float* __restrict__ bbu,
    const float* __restrict__ Wss3, const float* __restrict__ bss3,
    const float* __restrict__ Wss8, const float* __restrict__ bss8,
    float* __restrict__ out) {
    const int r = blockIdx.x * 4 + (threadIdx.x >> 6);
    const int lane = threadIdx.x & 63;
    const u16* xr = xin + (size_t)r * 1024 + lane * 16;
    uint4 q0 = *(const uint4*)xr;
    uint4 q1 = *(const uint4*)(xr + 8);
    float xv[16];
    u32 qs[8] = { q0.x, q0.y, q0.z, q0.w, q1.x, q1.y, q1.z, q1.w };
#pragma unroll
    for (int i = 0; i < 8; ++i) {
        xv[i * 2]     = fmaxf(__uint_as_float((qs[i] & 0xffffu) << 16), 0.0f);
        xv[i * 2 + 1] = fmaxf(__uint_as_float(qs[i] & 0xffff0000u), 0.0f);
    }
    float acc[15] = {};
    const int k0 = lane * 16;
#pragma unroll
    for (int kk = 0; kk < 16; kk++) {
        float xk = xv[kk];
        int k = k0 + kk;
        acc[0] += xk * Wp[k * 2];      acc[1] += xk * Wp[k * 2 + 1];
        acc[2] += xk * Wbu[k * 2];     acc[3] += xk * Wbu[k * 2 + 1];
        acc[4] += xk * Wss3[k * 3];    acc[5] += xk * Wss3[k * 3 + 1];
        acc[6] += xk * Wss3[k * 3 + 2];
#pragma unroll
        for (int o = 0; o < 8; o++) acc[7 + o] += xk * Wss8[k * 8 + o];
    }
#pragma unroll
    for (int o = 0; o < 15; o++) {
#pragma unroll
        for (int off = 32; off; off >>= 1) acc[o] += __shfl_xor(acc[o], off, 64);
    }
    if (lane == 0) {
        float a0 = acc[0] + bp[0], a1 = acc[1] + bp[1];
        float mx = fmaxf(a0, a1);
        float e0 = expf(a0 - mx), e1 = expf(a1 - mx);
        float ssum = e0 + e1;
        out[(size_t)r * 2] = e0 / ssum;
        out[(size_t)r * 2 + 1] = e1 / ssum;
        float* ob = out + 65536;
        ob[r * 2] = acc[2] + bbu[0]; ob[r * 2 + 1] = acc[3] + bbu[1];
        float* o3 = out + 131072;
        o3[r * 3 + 0] = acc[4] + bss3[0];
        o3[r * 3 + 1] = acc[5] + bss3[1];
        o3[r * 3 + 2] = acc[6] + bss3[2];
        float* o8 = out + 229376;
#pragma unroll
        for (int o = 0; o < 8; o++) o8[r * 8 + o] = acc[7 + o] + bss8[o];
    }
}

// ---------------------------------------------------------------- launch
extern "C" void kernel_launch(void* const* d_in, const int* in_sizes, int n_in,
                              void* d_out, int out_size, void* d_ws, size_t ws_size,
                              hipStream_t stream) {
    const float* x = (const float*)d_in[0];
    const int* xmask = (const int*)d_in[1];
    const float* Wf = (const float*)d_in[2];
    const float* Uf = (const float*)d_in[3];
    const float* bfp = (const float*)d_in[4];
    const float* Wb = (const float*)d_in[5];
    const float* Ub = (const float*)d_in[6];
    const float* bbp = (const float*)d_in[7];
    const float* Wp = (const float*)d_in[8];
    const float* bp = (const float*)d_in[9];
    const float* Wbu = (const float*)d_in[10];
    const float* bbu = (const float*)d_in[11];
    const float* Wss3 = (const float*)d_in[12];
    const float* bss3 = (const float*)d_in[13];
    const float* Wss8 = (const float*)d_in[14];
    const float* bss8 = (const float*)d_in[15];

    char* wsb = (char*)d_ws;
    u16* actA = (u16*)wsb;                               // 64 MB
    u16* actB = (u16*)(wsb + (64ull << 20));             // 64 MB
    u16* wt   = (u16*)(wsb + (128ull << 20));            // 24 MB
    u16* upk  = (u16*)(wsb + (152ull << 20));            // 12 MB
    char* stb = wsb + (164ull << 20);                    // states
    u32* hbuf32 = (u32*)stb;                             // 131072 B
    float* cst = (float*)(stb + 131072);                 // 131072 B
    float* hst = (float*)(stb + 262144);                 // 131072 B
    u32* flags = (u32*)(stb + 393216);                   // 128 B packed
    u32* cnt   = (u32*)(stb + 393344);                   // 64 B counters
    const int stateFloats = (393344 + 64) / 4;

    size_t fixedB = 165ull << 20;
    u16* zf = (u16*)(wsb + fixedB);
    u16* zb = zf + (size_t)B_ * T_ * 2048;

    conv_bf16<<<dim3(8388608 / 256), 256, 0, stream>>>(x, actA);
    transpose_w<<<dim3(32, 16, 6), 256, 0, stream>>>(Wf, Wb, wt);
    pack_u<<<dim3(512, 6), 256, 0, stream>>>(Uf, Ub, upk);

    const u16* cur = actA;
    for (int l = 0; l < 3; l++) {
        u16* dst = (l & 1) ? actA : actB;
        zero_mem<<<dim3((stateFloats + 255) / 256), 256, 0, stream>>>(
            (float*)stb, stateFloats);
        u16* wtf = wt + (size_t)(l * 2 + 0) * NG * 1024;
        u16* wtb = wt + (size_t)(l * 2 + 1) * NG * 1024;
        const u16* upkl = upk + (size_t)l * 2 * 1048576;
        const float* bfl = bfp + l * NG;
        const float* bbl = bbp + l * NG;

        const u16* a_act = cur;
        const u16* a_wtf = wtf; const u16* a_wtb = wtb;
        const float* a_bf = bfl; const float* a_bb = bbl;
        u16* a_zf = zf; u16* a_zb = zb;
        const u16* a_up = upkl; const int* a_xm = xmask;
        u32* a_hb = hbuf32; float* a_cs = cst; float* a_hs = hst;
        u32* a_fl = flags; u32* a_cnt = cnt; u16* a_hseq = dst;
        void* kargs[] = { &a_act, &a_wtf, &a_wtb, &a_bf, &a_bb, &a_zf, &a_zb,
                          &a_up, &a_xm, &a_hb, &a_cs, &a_hs, &a_fl, &a_cnt,
                          &a_hseq };
        hipLaunchCooperativeKernel((void*)fused_layer, dim3(256), dim3(512),
                                   kargs, 0, stream);
        cur = dst;
    }
    heads_kernel<<<dim3(B_ * T_ / 4), 256, 0, stream>>>(
        cur, Wp, bp, Wbu, bbu, Wss3, bss3, Wss8, bss8, (float*)d_out);
}

// Round 13
// 11724.471 us; speedup vs baseline: 1.1577x; 1.0408x over previous
//
#include <hip/hip_runtime.h>
#include <hip/hip_bf16.h>
#include <math.h>

// 3-layer masked BiLSTM (B=32,T=1024,D=1024,H=512) + 4 heads.
// Round 13: r12 fused structure, producer count halved (64 wgs/dir, 128
// total) to cut fabric interference with the latency-critical recurrence
// RTT chain. Production keeps 2x slack per t-block.

#define B_ 32
#define T_ 1024
#define H_ 512
#define NG 2048   // 4*H

typedef __attribute__((ext_vector_type(8))) short bf16x8;
typedef __attribute__((ext_vector_type(4))) float f32x4;
typedef unsigned int u32;
typedef unsigned long long u64;
typedef unsigned short u16;

__device__ inline u16 f2bf(float f) {          // round-to-nearest-even
    u32 u = __float_as_uint(f);
    return (u16)((u + 0x7fffu + ((u >> 16) & 1u)) >> 16);
}
__device__ inline float bf2f(u16 v) { return __uint_as_float(((u32)v) << 16); }
__device__ inline void gload16(const void* g, void* l) {
    __builtin_amdgcn_global_load_lds(
        (const __attribute__((address_space(1))) u32*)g,
        (__attribute__((address_space(3))) u32*)l, 16, 0, 0);
}
__device__ inline float fsig(float x) { return 1.0f / (1.0f + __expf(-x)); }
__device__ inline float ftanh(float x) { return 1.0f - 2.0f / (__expf(2.0f * x) + 1.0f); }

// ---------------------------------------------------------------- zero
__global__ void zero_mem(float* __restrict__ s, int n) {
    int i = blockIdx.x * 256 + threadIdx.x;
    if (i < n) s[i] = 0.0f;
}

// ---------------------------------------------------------------- fp32 -> bf16
__global__ __launch_bounds__(256) void conv_bf16(const float* __restrict__ src,
                                                 u16* __restrict__ dst) {
    int i = blockIdx.x * 256 + threadIdx.x;
    float4 v = *(const float4*)&src[(size_t)i * 4];
    ushort4 o = { f2bf(v.x), f2bf(v.y), f2bf(v.z), f2bf(v.w) };
    *(ushort4*)&dst[(size_t)i * 4] = o;
}

// ---------------------------------------------------------------- W transpose
// W [1024][2048] fp32  ->  wt [2048][1024] bf16   (6 matrices: l*2+dir)
__global__ __launch_bounds__(256) void transpose_w(const float* __restrict__ Wf,
                                                   const float* __restrict__ Wb,
                                                   u16* __restrict__ wt) {
    int mat = blockIdx.z;
    const float* W = ((mat & 1) ? Wb : Wf) + (size_t)(mat >> 1) * 1024 * NG;
    u16* dst = wt + (size_t)mat * NG * 1024;
    __shared__ float tile[64][65];
    int n0 = blockIdx.x * 64, k0 = blockIdx.y * 64;
    int t = threadIdx.x;
#pragma unroll
    for (int i = 0; i < 16; ++i) {
        int idx = t + i * 256;
        int kk = idx >> 6, nn = idx & 63;
        tile[kk][nn] = W[(size_t)(k0 + kk) * NG + n0 + nn];
    }
    __syncthreads();
#pragma unroll
    for (int i = 0; i < 16; ++i) {
        int idx = t + i * 256;
        int nn = idx >> 6, kk = idx & 63;
        dst[(size_t)(n0 + nn) * 1024 + k0 + kk] = f2bf(tile[kk][nn]);
    }
}

// ---------------------------------------------------------------- U pack (r9)
// U [512][2048] fp32 -> MFMA B-fragment order, bf16.
__global__ __launch_bounds__(256) void pack_u(const float* __restrict__ Uf,
                                              const float* __restrict__ Ub,
                                              u16* __restrict__ upk) {
    int mat = blockIdx.y;               // l*2 + dir
    const float* U = ((mat & 1) ? Ub : Uf) + (size_t)(mat >> 1) * H_ * NG;
    u16* dst = upk + (size_t)mat * 1048576;
    int f = blockIdx.x * 256 + threadIdx.x;
    int lane = f & 63, ks = (f >> 6) & 15, c2 = (f >> 10) & 1;
    int cp = (f >> 11) & 3, wg = f >> 13;
    int col = cp * H_ + wg * 32 + c2 * 16 + (lane & 15);
    int krow = ks * 32 + (lane >> 4) * 8;
    u16 o[8];
#pragma unroll
    for (int j = 0; j < 8; ++j) o[j] = f2bf(U[(size_t)(krow + j) * NG + col]);
    *(uint4*)(dst + (size_t)f * 8) = *(uint4*)o;
}

// ---------------------------------------------------------------- fused layer
// 160 wgs x 512 threads, cooperative. wgs 0-31: recurrence (r9 body).
// wgs 32-159: z-GEMM, 64 per dir, tiles in consumption order.
__global__ __launch_bounds__(512, 1) void fused_layer(
    const u16* __restrict__ act,          // [B*T][1024] bf16
    const u16* __restrict__ wtf, const u16* __restrict__ wtb,  // [2048][1024]
    const float* __restrict__ bfl, const float* __restrict__ bbl,
    u16* __restrict__ zf, u16* __restrict__ zb,   // [B*T][2048] gate-ilv bf16
    const u16* __restrict__ upk,          // [2 dirs][1048576]
    const int* __restrict__ xmask,
    u32* __restrict__ hbuf32,             // [2 dir][2 parity][8192] u32
    float* __restrict__ cst, float* __restrict__ hst,  // [2*16384]
    u32* __restrict__ flags,              // [2][16] packed
    u32* __restrict__ cnt,                // [2][8] t-block tile counters
    u16* __restrict__ hseq) {             // [B][T][1024] bf16
    const int bx = blockIdx.x;
    const int tid = threadIdx.x;
    const int wave = tid >> 6, lane = tid & 63;
    const int fr = lane & 15, fq = lane >> 4;

    __shared__ __align__(16) u16 sh[16384];       // 32KB (recur: h / gemm: A+B)
    __shared__ float sacc[32 * 132];              // recur gate preacts

    if (bx >= 32) {
        // ---------------- GEMM producer (64 wgs per dir) ----------------
        const int g = bx - 32;
        const int dir = (g >= 64) ? 1 : 0;
        const int local = dir ? g - 64 : g;
        const u16* Bt = dir ? wtb : wtf;
        const float* bias = dir ? bbl : bfl;
        u16* Zb = dir ? zb : zf;
        u32* mycnt = cnt + dir * 8;
        u16* sA = sh;                 // [128][32]
        u16* sB = sh + 4096;          // [128][32]
        const int r = tid >> 2, kp = (tid & 3) * 8;
        const int wr = (wave & 1) * 64, wc = (wave >> 1) * 32;
        for (int i = local; i < 4096; i += 64) {
            int tb_ord = i >> 9, within = i & 511;
            int b = within >> 4, nt = within & 15;
            int tb = dir ? 7 - tb_ord : tb_ord;
            int m0 = b * 1024 + tb * 128;
            int n0 = nt * 128;
            const size_t arow = (size_t)(m0 + r) * 1024;   // act row == m
            const size_t brow = (size_t)(n0 + r) * 1024;
            f32x4 acc[4][2] = {};
            for (int kc = 0; kc < 1024; kc += 32) {
                gload16(act + arow + kc + kp, sA + tid * 8);
                gload16(Bt + brow + kc + kp, sB + tid * 8);
                __syncthreads();
                bf16x8 af[4], bfr[2];
                const int fk = fq * 8;
#pragma unroll
                for (int ii = 0; ii < 4; ++ii)
                    af[ii] = *(const bf16x8*)&sA[(wr + ii * 16 + fr) * 32 + fk];
#pragma unroll
                for (int j = 0; j < 2; ++j)
                    bfr[j] = *(const bf16x8*)&sB[(wc + j * 16 + fr) * 32 + fk];
#pragma unroll
                for (int ii = 0; ii < 4; ++ii)
#pragma unroll
                    for (int j = 0; j < 2; ++j)
                        acc[ii][j] = __builtin_amdgcn_mfma_f32_16x16x32_bf16(
                            af[ii], bfr[j], acc[ii][j], 0, 0, 0);
                __syncthreads();
            }
            float bv[2]; int un[2], gn[2];
#pragma unroll
            for (int j = 0; j < 2; ++j) {
                int n = n0 + wc + j * 16 + fr;
                bv[j] = bias[n];
                un[j] = n & 511; gn[j] = n >> 9;
            }
#pragma unroll
            for (int ii = 0; ii < 4; ++ii) {
                int mb = m0 + wr + ii * 16 + fq * 4;
#pragma unroll
                for (int j = 0; j < 2; ++j)
#pragma unroll
                    for (int rr = 0; rr < 4; ++rr)
                        Zb[(size_t)(mb + rr) * 2048 + un[j] * 4 + gn[j]] =
                            f2bf(acc[ii][j][rr] + bv[j]);
            }
            __syncthreads();          // all threads' stores complete (in L2)
            if (tid == 0) {
                __threadfence();      // wbl2: push tile to coherence point
                __hip_atomic_fetch_add(mycnt + tb, 1u, __ATOMIC_RELAXED,
                                       __HIP_MEMORY_SCOPE_AGENT);
            }
        }
        return;
    }

    // ---------------- recurrence (r9 body + z atomic u64 + tb gating) -------
    const int dir = bx >> 4, wgs = bx & 15, u0 = wgs * 32;
    const u64* z64 = (const u64*)(dir ? zb : zf);   // u64 idx = row*512 + u
    const u16* up = upk + dir * 1048576;
    u32* hb32 = hbuf32 + dir * 16384;
    u32* myflag = flags + dir * 16 + wgs;
    const u32* fbase = flags + dir * 16;
    const u32* ctb = cnt + dir * 8;
    const int cp = wave & 3, bt = wave >> 2;
    const int row = bt * 16 + fr;                 // batch index for B frags
    const int swz = (row & 7) << 4;

    // U fragments -> registers (stationary across the layer)
    bf16x8 uf0[16], uf1[16];
#pragma unroll
    for (int ks = 0; ks < 16; ++ks) {
        size_t base0 = (((size_t)(wgs * 4 + cp) * 2) * 16 + ks) * 512 + lane * 8;
        uf0[ks] = *(const bf16x8*)(up + base0);
        uf1[ks] = *(const bf16x8*)(up + base0 + 16 * 512);
    }

    const int b0p = tid >> 5, ul = tid & 31, b1p = b0p + 16, ug = u0 + ul;
    const int sidx = (dir * 16 + wgs) * 1024 + tid * 2;
    float c0r = cst[sidx], c1r = cst[sidx + 1];
    float h0r = hst[sidx], h1r = hst[sidx + 1];
    const size_t hs0 = (size_t)b0p * T_ * 1024 + dir * 512 + ug;
    const size_t hs1 = (size_t)b1p * T_ * 1024 + dir * 512 + ug;

    int haveb = -1;
    auto wait_tb = [&](int tb) {
        if (tb == haveb) return;
        const u32* cpp = ctb + tb;
        u32 v = 512;
        if (lane == 0) v = __hip_atomic_load(cpp, __ATOMIC_RELAXED,
                                             __HIP_MEMORY_SCOPE_AGENT);
        while (!__all(v >= 512)) {
            if (lane == 0) v = __hip_atomic_load(cpp, __ATOMIC_RELAXED,
                                                 __HIP_MEMORY_SCOPE_AGENT);
        }
        haveb = tb;
    };

    // prologue: stage parity-0 h into LDS (agent atomic loads + swizzled write)
    {
        u32 tmp[16];
#pragma unroll
        for (int k = 0; k < 16; ++k)
            tmp[k] = __hip_atomic_load(hb32 + k * 512 + tid, __ATOMIC_RELAXED,
                                       __HIP_MEMORY_SCOPE_AGENT);
#pragma unroll
        for (int k = 0; k < 16; ++k) {
            int idx = k * 512 + tid;
            int sb = (idx * 4) ^ (((idx >> 8) & 7) << 4);
            *(u32*)((char*)sh + sb) = tmp[k];
        }
    }
    // z/mask for step 0 (gated on its t-block)
    u64 za0, za1; int mc0, mc1;
    {
        int tc = dir ? (T_ - 1) : 0;
        wait_tb(tc >> 7);
        za0 = __hip_atomic_load(z64 + (size_t)(b0p * T_ + tc) * 512 + ug,
                                __ATOMIC_RELAXED, __HIP_MEMORY_SCOPE_AGENT);
        za1 = __hip_atomic_load(z64 + (size_t)(b1p * T_ + tc) * 512 + ug,
                                __ATOMIC_RELAXED, __HIP_MEMORY_SCOPE_AGENT);
        mc0 = xmask[b0p * T_ + tc]; mc1 = xmask[b1p * T_ + tc];
    }
    __syncthreads();

    u16 hb0s = 0, hb1s = 0;
    for (int st = 0; st < T_; ++st) {
        const int t = dir ? (T_ - 1 - st) : st;
        u32* nx32 = hb32 + (((st & 1) ^ 1) ? 8192 : 0);

        // MFMA from LDS (swizzled) x register U, over K=512
        f32x4 acc0 = {0, 0, 0, 0}, acc1 = {0, 0, 0, 0};
#pragma unroll
        for (int ks = 0; ks < 16; ++ks) {
            int abyte = (row * 1024 + ks * 64 + fq * 16) ^ swz;
            bf16x8 a = *(const bf16x8*)((const char*)sh + abyte);
            acc0 = __builtin_amdgcn_mfma_f32_16x16x32_bf16(a, uf0[ks], acc0, 0, 0, 0);
            acc1 = __builtin_amdgcn_mfma_f32_16x16x32_bf16(a, uf1[ks], acc1, 0, 0, 0);
        }
#pragma unroll
        for (int j = 0; j < 4; ++j) {
            int b = bt * 16 + fq * 4 + j;
            sacc[b * 132 + cp * 32 + fr] = acc0[j];
            sacc[b * 132 + cp * 32 + 16 + fr] = acc1[j];
        }
        __syncthreads();                               // A: sacc visible
        // pointwise gates + state update + coherent h stores
        {
            const float* s0 = sacc + b0p * 132;
            const float* s1 = sacc + b1p * 132;
            float i0 = fsig(bf2f((u16)za0) + s0[ul]);
            float f0 = fsig(bf2f((u16)(za0 >> 16)) + s0[32 + ul]);
            float g0 = ftanh(bf2f((u16)(za0 >> 32)) + s0[64 + ul]);
            float o0 = fsig(bf2f((u16)(za0 >> 48)) + s0[96 + ul]);
            if (mc0 != 1) { c0r = f0 * c0r + i0 * g0; h0r = o0 * ftanh(c0r); }
            float i1 = fsig(bf2f((u16)za1) + s1[ul]);
            float f1 = fsig(bf2f((u16)(za1 >> 16)) + s1[32 + ul]);
            float g1 = ftanh(bf2f((u16)(za1 >> 32)) + s1[64 + ul]);
            float o1 = fsig(bf2f((u16)(za1 >> 48)) + s1[96 + ul]);
            if (mc1 != 1) { c1r = f1 * c1r + i1 * g1; h1r = o1 * ftanh(c1r); }
            hb0s = f2bf(h0r); hb1s = f2bf(h1r);
            u32 nb0 = __shfl_xor((u32)hb0s, 1, 64);
            u32 nb1 = __shfl_xor((u32)hb1s, 1, 64);
            if ((ul & 1) == 0) {
                u32 pk0 = (u32)hb0s | (nb0 << 16);
                u32 pk1 = (u32)hb1s | (nb1 << 16);
                __hip_atomic_store(nx32 + b0p * 256 + (ug >> 1), pk0,
                                   __ATOMIC_RELAXED, __HIP_MEMORY_SCOPE_AGENT);
                __hip_atomic_store(nx32 + b1p * 256 + (ug >> 1), pk1,
                                   __ATOMIC_RELAXED, __HIP_MEMORY_SCOPE_AGENT);
            }
        }
        __syncthreads();   // B: implicit vmcnt(0) drains every thread's stores
        const u32 tgt = (u32)(st + 1);
        if (tid == 0)
            __hip_atomic_store(myflag, tgt, __ATOMIC_RELAXED,
                               __HIP_MEMORY_SCOPE_AGENT);
        // hseq stores: fire-and-forget, hidden under poll+stage
        hseq[hs0 + (size_t)t * 1024] = hb0s;
        hseq[hs1 + (size_t)t * 1024] = hb1s;
        // prefetch next-step z/mask (flies during the poll)
        u64 zn0 = 0, zn1 = 0; int mn0 = 0, mn1 = 0;
        {
            int stn = (st + 1 < T_) ? st + 1 : st;
            int tcn = dir ? (T_ - 1 - stn) : stn;
            wait_tb(tcn >> 7);
            zn0 = __hip_atomic_load(z64 + (size_t)(b0p * T_ + tcn) * 512 + ug,
                                    __ATOMIC_RELAXED, __HIP_MEMORY_SCOPE_AGENT);
            zn1 = __hip_atomic_load(z64 + (size_t)(b1p * T_ + tcn) * 512 + ug,
                                    __ATOMIC_RELAXED, __HIP_MEMORY_SCOPE_AGENT);
            mn0 = xmask[b0p * T_ + tcn]; mn1 = xmask[b1p * T_ + tcn];
        }
        // per-wave poll of the packed flag line (lanes<16 issue loads)
        {
            u32 v = 0xffffffffu;
            if (lane < 16)
                v = __hip_atomic_load(fbase + lane, __ATOMIC_RELAXED,
                                      __HIP_MEMORY_SCOPE_AGENT);
            while (!__all(v >= tgt)) {
                if (lane < 16)
                    v = __hip_atomic_load(fbase + lane, __ATOMIC_RELAXED,
                                          __HIP_MEMORY_SCOPE_AGENT);
            }
        }
        // stage next-parity h into LDS (coalesced agent loads, swizzled write)
        if (st + 1 < T_) {
            const u32* src = hb32 + (((st + 1) & 1) ? 8192 : 0);
            u32 tmp[16];
#pragma unroll
            for (int k = 0; k < 16; ++k)
                tmp[k] = __hip_atomic_load(src + k * 512 + tid, __ATOMIC_RELAXED,
                                           __HIP_MEMORY_SCOPE_AGENT);
#pragma unroll
            for (int k = 0; k < 16; ++k) {
                int idx = k * 512 + tid;
                int sb = (idx * 4) ^ (((idx >> 8) & 7) << 4);
                *(u32*)((char*)sh + sb) = tmp[k];
            }
        }
        za0 = zn0; za1 = zn1; mc0 = mn0; mc1 = mn1;
        __syncthreads();                               // C: sh staged by all
    }
    cst[sidx] = c0r; cst[sidx + 1] = c1r;
    hst[sidx] = h0r; hst[sidx + 1] = h1r;
}

// ---------------------------------------------------------------- heads
__global__ __launch_bounds__(256) void heads_kernel(
    const u16* __restrict__ xin,
    const float* __restrict__ Wp, const float* __restrict__ bp,
    const float* __restrict__ Wbu, const float* __restrict__ bbu,
    const float* __restrict__ Wss3, const float* __restrict__ bss3,
    const float* __restrict__ Wss8, const float* __restrict__ bss8,
    float* __restrict__ out) {
    const int r = blockIdx.x * 4 + (threadIdx.x >> 6);
    const int lane = threadIdx.x & 63;
    const u16* xr = xin + (size_t)r * 1024 + lane * 16;
    uint4 q0 = *(const uint4*)xr;
    uint4 q1 = *(const uint4*)(xr + 8);
    float xv[16];
    u32 qs[8] = { q0.x, q0.y, q0.z, q0.w, q1.x, q1.y, q1.z, q1.w };
#pragma unroll
    for (int i = 0; i < 8; ++i) {
        xv[i * 2]     = fmaxf(__uint_as_float((qs[i] & 0xffffu) << 16), 0.0f);
        xv[i * 2 + 1] = fmaxf(__uint_as_float(qs[i] & 0xffff0000u), 0.0f);
    }
    float acc[15] = {};
    const int k0 = lane * 16;
#pragma unroll
    for (int kk = 0; kk < 16; kk++) {
        float xk = xv[kk];
        int k = k0 + kk;
        acc[0] += xk * Wp[k * 2];      acc[1] += xk * Wp[k * 2 + 1];
        acc[2] += xk * Wbu[k * 2];     acc[3] += xk * Wbu[k * 2 + 1];
        acc[4] += xk * Wss3[k * 3];    acc[5] += xk * Wss3[k * 3 + 1];
        acc[6] += xk * Wss3[k * 3 + 2];
#pragma unroll
        for (int o = 0; o < 8; o++) acc[7 + o] += xk * Wss8[k * 8 + o];
    }
#pragma unroll
    for (int o = 0; o < 15; o++) {
#pragma unroll
        for (int off = 32; off; off >>= 1) acc[o] += __shfl_xor(acc[o], off, 64);
    }
    if (lane == 0) {
        float a0 = acc[0] + bp[0], a1 = acc[1] + bp[1];
        float mx = fmaxf(a0, a1);
        float e0 = expf(a0 - mx), e1 = expf(a1 - mx);
        float ssum = e0 + e1;
        out[(size_t)r * 2] = e0 / ssum;
        out[(size_t)r * 2 + 1] = e1 / ssum;
        float* ob = out + 65536;
        ob[r * 2] = acc[2] + bbu[0]; ob[r * 2 + 1] = acc[3] + bbu[1];
        float* o3 = out + 131072;
        o3[r * 3 + 0] = acc[4] + bss3[0];
        o3[r * 3 + 1] = acc[5] + bss3[1];
        o3[r * 3 + 2] = acc[6] + bss3[2];
        float* o8 = out + 229376;
#pragma unroll
        for (int o = 0; o < 8; o++) o8[r * 8 + o] = acc[7 + o] + bss8[o];
    }
}

// ---------------------------------------------------------------- launch
extern "C" void kernel_launch(void* const* d_in, const int* in_sizes, int n_in,
                              void* d_out, int out_size, void* d_ws, size_t ws_size,
                              hipStream_t stream) {
    const float* x = (const float*)d_in[0];
    const int* xmask = (const int*)d_in[1];
    const float* Wf = (const float*)d_in[2];
    const float* Uf = (const float*)d_in[3];
    const float* bfp = (const float*)d_in[4];
    const float* Wb = (const float*)d_in[5];
    const float* Ub = (const float*)d_in[6];
    const float* bbp = (const float*)d_in[7];
    const float* Wp = (const float*)d_in[8];
    const float* bp = (const float*)d_in[9];
    const float* Wbu = (const float*)d_in[10];
    const float* bbu = (const float*)d_in[11];
    const float* Wss3 = (const float*)d_in[12];
    const float* bss3 = (const float*)d_in[13];
    const float* Wss8 = (const float*)d_in[14];
    const float* bss8 = (const float*)d_in[15];

    char* wsb = (char*)d_ws;
    u16* actA = (u16*)wsb;                               // 64 MB
    u16* actB = (u16*)(wsb + (64ull << 20));             // 64 MB
    u16* wt   = (u16*)(wsb + (128ull << 20));            // 24 MB
    u16* upk  = (u16*)(wsb + (152ull << 20));            // 12 MB
    char* stb = wsb + (164ull << 20);                    // states
    u32* hbuf32 = (u32*)stb;                             // 131072 B
    float* cst = (float*)(stb + 131072);                 // 131072 B
    float* hst = (float*)(stb + 262144);                 // 131072 B
    u32* flags = (u32*)(stb + 393216);                   // 128 B packed
    u32* cnt   = (u32*)(stb + 393344);                   // 64 B counters
    const int stateFloats = (393344 + 64) / 4;

    size_t fixedB = 165ull << 20;
    u16* zf = (u16*)(wsb + fixedB);
    u16* zb = zf + (size_t)B_ * T_ * 2048;

    conv_bf16<<<dim3(8388608 / 256), 256, 0, stream>>>(x, actA);
    transpose_w<<<dim3(32, 16, 6), 256, 0, stream>>>(Wf, Wb, wt);
    pack_u<<<dim3(512, 6), 256, 0, stream>>>(Uf, Ub, upk);

    const u16* cur = actA;
    for (int l = 0; l < 3; l++) {
        u16* dst = (l & 1) ? actA : actB;
        zero_mem<<<dim3((stateFloats + 255) / 256), 256, 0, stream>>>(
            (float*)stb, stateFloats);
        u16* wtf = wt + (size_t)(l * 2 + 0) * NG * 1024;
        u16* wtb = wt + (size_t)(l * 2 + 1) * NG * 1024;
        const u16* upkl = upk + (size_t)l * 2 * 1048576;
        const float* bfl = bfp + l * NG;
        const float* bbl = bbp + l * NG;

        const u16* a_act = cur;
        const u16* a_wtf = wtf; const u16* a_wtb = wtb;
        const float* a_bf = bfl; const float* a_bb = bbl;
        u16* a_zf = zf; u16* a_zb = zb;
        const u16* a_up = upkl; const int* a_xm = xmask;
        u32* a_hb = hbuf32; float* a_cs = cst; float* a_hs = hst;
        u32* a_fl = flags; u32* a_cnt = cnt; u16* a_hseq = dst;
        void* kargs[] = { &a_act, &a_wtf, &a_wtb, &a_bf, &a_bb, &a_zf, &a_zb,
                          &a_up, &a_xm, &a_hb, &a_cs, &a_hs, &a_fl, &a_cnt,
                          &a_hseq };
        hipLaunchCooperativeKernel((void*)fused_layer, dim3(160), dim3(512),
                                   kargs, 0, stream);
        cur = dst;
    }
    heads_kernel<<<dim3(B_ * T_ / 4), 256, 0, stream>>>(
        cur, Wp, bp, Wbu, bbu, Wss3, bss3, Wss8, bss8, (float*)d_out);
}

// Round 14
// 9962.752 us; speedup vs baseline: 1.3624x; 1.1768x over previous
//
#include <hip/hip_runtime.h>
#include <hip/hip_bf16.h>
#include <math.h>

// 3-layer masked BiLSTM (B=32,T=1024,D=1024,H=512) + 4 heads.
// Round 14: r13 + XCD-local recurrence. Hang-proof claim protocol (agent
// atomics + monotone-counter consensus, no grid.sync, no sc0): each dir's
// 16 recurrence wgs land on ONE XCD so the per-step h/flag exchange can be
// served by that XCD's L2. Correctness never depends on placement.

#define B_ 32
#define T_ 1024
#define H_ 512
#define NG 2048   // 4*H
#define NWG 160

typedef __attribute__((ext_vector_type(8))) short bf16x8;
typedef __attribute__((ext_vector_type(4))) float f32x4;
typedef unsigned int u32;
typedef unsigned long long u64;
typedef unsigned short u16;

__device__ inline u16 f2bf(float f) {          // round-to-nearest-even
    u32 u = __float_as_uint(f);
    return (u16)((u + 0x7fffu + ((u >> 16) & 1u)) >> 16);
}
__device__ inline float bf2f(u16 v) { return __uint_as_float(((u32)v) << 16); }
__device__ inline void gload16(const void* g, void* l) {
    __builtin_amdgcn_global_load_lds(
        (const __attribute__((address_space(1))) u32*)g,
        (__attribute__((address_space(3))) u32*)l, 16, 0, 0);
}
__device__ inline float fsig(float x) { return 1.0f / (1.0f + __expf(-x)); }
__device__ inline float ftanh(float x) { return 1.0f - 2.0f / (__expf(2.0f * x) + 1.0f); }

// ---------------------------------------------------------------- zero
__global__ void zero_mem(float* __restrict__ s, int n) {
    int i = blockIdx.x * 256 + threadIdx.x;
    if (i < n) s[i] = 0.0f;
}

// ---------------------------------------------------------------- fp32 -> bf16
__global__ __launch_bounds__(256) void conv_bf16(const float* __restrict__ src,
                                                 u16* __restrict__ dst) {
    int i = blockIdx.x * 256 + threadIdx.x;
    float4 v = *(const float4*)&src[(size_t)i * 4];
    ushort4 o = { f2bf(v.x), f2bf(v.y), f2bf(v.z), f2bf(v.w) };
    *(ushort4*)&dst[(size_t)i * 4] = o;
}

// ---------------------------------------------------------------- W transpose
// W [1024][2048] fp32  ->  wt [2048][1024] bf16   (6 matrices: l*2+dir)
__global__ __launch_bounds__(256) void transpose_w(const float* __restrict__ Wf,
                                                   const float* __restrict__ Wb,
                                                   u16* __restrict__ wt) {
    int mat = blockIdx.z;
    const float* W = ((mat & 1) ? Wb : Wf) + (size_t)(mat >> 1) * 1024 * NG;
    u16* dst = wt + (size_t)mat * NG * 1024;
    __shared__ float tile[64][65];
    int n0 = blockIdx.x * 64, k0 = blockIdx.y * 64;
    int t = threadIdx.x;
#pragma unroll
    for (int i = 0; i < 16; ++i) {
        int idx = t + i * 256;
        int kk = idx >> 6, nn = idx & 63;
        tile[kk][nn] = W[(size_t)(k0 + kk) * NG + n0 + nn];
    }
    __syncthreads();
#pragma unroll
    for (int i = 0; i < 16; ++i) {
        int idx = t + i * 256;
        int nn = idx >> 6, kk = idx & 63;
        dst[(size_t)(n0 + nn) * 1024 + k0 + kk] = f2bf(tile[kk][nn]);
    }
}

// ---------------------------------------------------------------- U pack (r9)
// U [512][2048] fp32 -> MFMA B-fragment order, bf16.
__global__ __launch_bounds__(256) void pack_u(const float* __restrict__ Uf,
                                              const float* __restrict__ Ub,
                                              u16* __restrict__ upk) {
    int mat = blockIdx.y;               // l*2 + dir
    const float* U = ((mat & 1) ? Ub : Uf) + (size_t)(mat >> 1) * H_ * NG;
    u16* dst = upk + (size_t)mat * 1048576;
    int f = blockIdx.x * 256 + threadIdx.x;
    int lane = f & 63, ks = (f >> 6) & 15, c2 = (f >> 10) & 1;
    int cp = (f >> 11) & 3, wg = f >> 13;
    int col = cp * H_ + wg * 32 + c2 * 16 + (lane & 15);
    int krow = ks * 32 + (lane >> 4) * 8;
    u16 o[8];
#pragma unroll
    for (int j = 0; j < 8; ++j) o[j] = f2bf(U[(size_t)(krow + j) * NG + col]);
    *(uint4*)(dst + (size_t)f * 8) = *(uint4*)o;
}

// ---------------------------------------------------------------- fused layer
// 160 wgs x 512 threads, cooperative. Roles via XCD claim: 16 recurrence wgs
// per dir co-located on one XCD; 128 producers (64/dir).
__global__ __launch_bounds__(512, 1) void fused_layer(
    const u16* __restrict__ act,          // [B*T][1024] bf16
    const u16* __restrict__ wtf, const u16* __restrict__ wtb,  // [2048][1024]
    const float* __restrict__ bfl, const float* __restrict__ bbl,
    u16* __restrict__ zf, u16* __restrict__ zb,   // [B*T][2048] gate-ilv bf16
    const u16* __restrict__ upk,          // [2 dirs][1048576]
    const int* __restrict__ xmask,
    u32* __restrict__ hbuf32,             // [2 dir][2 parity][8192] u32
    float* __restrict__ cst, float* __restrict__ hst,  // [2*16384]
    u32* __restrict__ flags,              // [2][64] (256B per dir)
    u32* __restrict__ cnt,                // [2][8] t-block tile counters
    u32* __restrict__ claim,              // [16]: 0-7 xcd, 8 global, 9 prod
    u16* __restrict__ hseq) {             // [B][T][1024] bf16
    const int tid = threadIdx.x;
    const int wave = tid >> 6, lane = tid & 63;
    const int fr = lane & 15, fq = lane >> 4;

    __shared__ __align__(16) u16 sh[16384];       // 32KB (recur: h / gemm: A+B)
    __shared__ float sacc[32 * 132];              // recur gate preacts
    __shared__ int s_role, s_dir, s_idx;

    // ---- role claim (hang-proof: increment-then-spin on monotone counters)
    if (tid == 0) {
        u32 myxcd = 0;
        asm volatile("s_getreg_b32 %0, hwreg(HW_REG_XCC_ID)" : "=s"(myxcd));
        myxcd &= 7;
        int myslot = (int)__hip_atomic_fetch_add(&claim[myxcd], 1u,
                         __ATOMIC_RELAXED, __HIP_MEMORY_SCOPE_AGENT);
        int total;
        do {
            total = 0;
#pragma unroll
            for (int i = 0; i < 8; ++i)
                total += (int)__hip_atomic_load(&claim[i], __ATOMIC_RELAXED,
                                                __HIP_MEMORY_SCOPE_AGENT);
        } while (total < NWG);
        int cv[8];
#pragma unroll
        for (int i = 0; i < 8; ++i)
            cv[i] = (int)__hip_atomic_load(&claim[i], __ATOMIC_RELAXED,
                                           __HIP_MEMORY_SCOPE_AGENT);
        int a = 0;
        for (int i = 1; i < 8; ++i) if (cv[i] > cv[a]) a = i;
        int b = -1, bc = -1;
        for (int i = 0; i < 8; ++i)
            if (i != a && cv[i] > bc) { bc = cv[i]; b = i; }
        int role = 1, dir = 0, idx = 0;
        if (cv[a] >= 16 && bc >= 16) {            // XCD-local mode
            if ((int)myxcd == a && myslot < 16) { role = 0; dir = 0; idx = myslot; }
            else if ((int)myxcd == b && myslot < 16) { role = 0; dir = 1; idx = myslot; }
        } else {                                  // fallback: global ranks
            int g = (int)__hip_atomic_fetch_add(&claim[8], 1u,
                         __ATOMIC_RELAXED, __HIP_MEMORY_SCOPE_AGENT);
            if (g < 16) { role = 0; dir = 0; idx = g; }
            else if (g < 32) { role = 0; dir = 1; idx = g - 16; }
        }
        if (role == 1)
            idx = (int)__hip_atomic_fetch_add(&claim[9], 1u,
                         __ATOMIC_RELAXED, __HIP_MEMORY_SCOPE_AGENT);
        s_role = role; s_dir = dir; s_idx = idx;
    }
    __syncthreads();
    const int role = s_role;

    if (role == 1) {
        // ---------------- GEMM producer (64 wgs per dir) ----------------
        const int p = s_idx;
        const int dir = (p >= 64) ? 1 : 0;
        const int local = p & 63;
        const u16* Bt = dir ? wtb : wtf;
        const float* bias = dir ? bbl : bfl;
        u16* Zb = dir ? zb : zf;
        u32* mycnt = cnt + dir * 8;
        u16* sA = sh;                 // [128][32]
        u16* sB = sh + 4096;          // [128][32]
        const int r = tid >> 2, kp = (tid & 3) * 8;
        const int wr = (wave & 1) * 64, wc = (wave >> 1) * 32;
        for (int i = local; i < 4096; i += 64) {
            int tb_ord = i >> 9, within = i & 511;
            int b = within >> 4, nt = within & 15;
            int tb = dir ? 7 - tb_ord : tb_ord;
            int m0 = b * 1024 + tb * 128;
            int n0 = nt * 128;
            const size_t arow = (size_t)(m0 + r) * 1024;   // act row == m
            const size_t brow = (size_t)(n0 + r) * 1024;
            f32x4 acc[4][2] = {};
            for (int kc = 0; kc < 1024; kc += 32) {
                gload16(act + arow + kc + kp, sA + tid * 8);
                gload16(Bt + brow + kc + kp, sB + tid * 8);
                __syncthreads();
                bf16x8 af[4], bfr[2];
                const int fk = fq * 8;
#pragma unroll
                for (int ii = 0; ii < 4; ++ii)
                    af[ii] = *(const bf16x8*)&sA[(wr + ii * 16 + fr) * 32 + fk];
#pragma unroll
                for (int j = 0; j < 2; ++j)
                    bfr[j] = *(const bf16x8*)&sB[(wc + j * 16 + fr) * 32 + fk];
#pragma unroll
                for (int ii = 0; ii < 4; ++ii)
#pragma unroll
                    for (int j = 0; j < 2; ++j)
                        acc[ii][j] = __builtin_amdgcn_mfma_f32_16x16x32_bf16(
                            af[ii], bfr[j], acc[ii][j], 0, 0, 0);
                __syncthreads();
            }
            float bv[2]; int un[2], gn[2];
#pragma unroll
            for (int j = 0; j < 2; ++j) {
                int n = n0 + wc + j * 16 + fr;
                bv[j] = bias[n];
                un[j] = n & 511; gn[j] = n >> 9;
            }
#pragma unroll
            for (int ii = 0; ii < 4; ++ii) {
                int mb = m0 + wr + ii * 16 + fq * 4;
#pragma unroll
                for (int j = 0; j < 2; ++j)
#pragma unroll
                    for (int rr = 0; rr < 4; ++rr)
                        Zb[(size_t)(mb + rr) * 2048 + un[j] * 4 + gn[j]] =
                            f2bf(acc[ii][j][rr] + bv[j]);
            }
            __syncthreads();          // all threads' stores complete (in L2)
            if (tid == 0) {
                __threadfence();      // wbl2: push tile to coherence point
                __hip_atomic_fetch_add(mycnt + tb, 1u, __ATOMIC_RELAXED,
                                       __HIP_MEMORY_SCOPE_AGENT);
            }
        }
        return;
    }

    // ---------------- recurrence (r13 body; dir/slice from claim) ----------
    const int dir = s_dir, wgs = s_idx, u0 = wgs * 32;
    const u64* z64 = (const u64*)(dir ? zb : zf);   // u64 idx = row*512 + u
    const u16* up = upk + dir * 1048576;
    u32* hb32 = hbuf32 + dir * 16384;
    u32* myflag = flags + dir * 64 + wgs;
    const u32* fbase = flags + dir * 64;
    const u32* ctb = cnt + dir * 8;
    const int cp = wave & 3, bt = wave >> 2;
    const int row = bt * 16 + fr;                 // batch index for B frags
    const int swz = (row & 7) << 4;

    // U fragments -> registers (stationary across the layer)
    bf16x8 uf0[16], uf1[16];
#pragma unroll
    for (int ks = 0; ks < 16; ++ks) {
        size_t base0 = (((size_t)(wgs * 4 + cp) * 2) * 16 + ks) * 512 + lane * 8;
        uf0[ks] = *(const bf16x8*)(up + base0);
        uf1[ks] = *(const bf16x8*)(up + base0 + 16 * 512);
    }

    const int b0p = tid >> 5, ul = tid & 31, b1p = b0p + 16, ug = u0 + ul;
    const int sidx = (dir * 16 + wgs) * 1024 + tid * 2;
    float c0r = cst[sidx], c1r = cst[sidx + 1];
    float h0r = hst[sidx], h1r = hst[sidx + 1];
    const size_t hs0 = (size_t)b0p * T_ * 1024 + dir * 512 + ug;
    const size_t hs1 = (size_t)b1p * T_ * 1024 + dir * 512 + ug;

    int haveb = -1;
    auto wait_tb = [&](int tb) {
        if (tb == haveb) return;
        const u32* cpp = ctb + tb;
        u32 v = 512;
        if (lane == 0) v = __hip_atomic_load(cpp, __ATOMIC_RELAXED,
                                             __HIP_MEMORY_SCOPE_AGENT);
        while (!__all(v >= 512)) {
            if (lane == 0) v = __hip_atomic_load(cpp, __ATOMIC_RELAXED,
                                                 __HIP_MEMORY_SCOPE_AGENT);
        }
        haveb = tb;
    };

    // prologue: stage parity-0 h into LDS (agent atomic loads + swizzled write)
    {
        u32 tmp[16];
#pragma unroll
        for (int k = 0; k < 16; ++k)
            tmp[k] = __hip_atomic_load(hb32 + k * 512 + tid, __ATOMIC_RELAXED,
                                       __HIP_MEMORY_SCOPE_AGENT);
#pragma unroll
        for (int k = 0; k < 16; ++k) {
            int idx = k * 512 + tid;
            int sb = (idx * 4) ^ (((idx >> 8) & 7) << 4);
            *(u32*)((char*)sh + sb) = tmp[k];
        }
    }
    // z/mask for step 0 (gated on its t-block)
    u64 za0, za1; int mc0, mc1;
    {
        int tc = dir ? (T_ - 1) : 0;
        wait_tb(tc >> 7);
        za0 = __hip_atomic_load(z64 + (size_t)(b0p * T_ + tc) * 512 + ug,
                                __ATOMIC_RELAXED, __HIP_MEMORY_SCOPE_AGENT);
        za1 = __hip_atomic_load(z64 + (size_t)(b1p * T_ + tc) * 512 + ug,
                                __ATOMIC_RELAXED, __HIP_MEMORY_SCOPE_AGENT);
        mc0 = xmask[b0p * T_ + tc]; mc1 = xmask[b1p * T_ + tc];
    }
    __syncthreads();

    u16 hb0s = 0, hb1s = 0;
    for (int st = 0; st < T_; ++st) {
        const int t = dir ? (T_ - 1 - st) : st;
        u32* nx32 = hb32 + (((st & 1) ^ 1) ? 8192 : 0);

        // MFMA from LDS (swizzled) x register U, over K=512
        f32x4 acc0 = {0, 0, 0, 0}, acc1 = {0, 0, 0, 0};
#pragma unroll
        for (int ks = 0; ks < 16; ++ks) {
            int abyte = (row * 1024 + ks * 64 + fq * 16) ^ swz;
            bf16x8 a = *(const bf16x8*)((const char*)sh + abyte);
            acc0 = __builtin_amdgcn_mfma_f32_16x16x32_bf16(a, uf0[ks], acc0, 0, 0, 0);
            acc1 = __builtin_amdgcn_mfma_f32_16x16x32_bf16(a, uf1[ks], acc1, 0, 0, 0);
        }
#pragma unroll
        for (int j = 0; j < 4; ++j) {
            int b = bt * 16 + fq * 4 + j;
            sacc[b * 132 + cp * 32 + fr] = acc0[j];
            sacc[b * 132 + cp * 32 + 16 + fr] = acc1[j];
        }
        __syncthreads();                               // A: sacc visible
        // pointwise gates + state update + coherent h stores
        {
            const float* s0 = sacc + b0p * 132;
            const float* s1 = sacc + b1p * 132;
            float i0 = fsig(bf2f((u16)za0) + s0[ul]);
            float f0 = fsig(bf2f((u16)(za0 >> 16)) + s0[32 + ul]);
            float g0 = ftanh(bf2f((u16)(za0 >> 32)) + s0[64 + ul]);
            float o0 = fsig(bf2f((u16)(za0 >> 48)) + s0[96 + ul]);
            if (mc0 != 1) { c0r = f0 * c0r + i0 * g0; h0r = o0 * ftanh(c0r); }
            float i1 = fsig(bf2f((u16)za1) + s1[ul]);
            float f1 = fsig(bf2f((u16)(za1 >> 16)) + s1[32 + ul]);
            float g1 = ftanh(bf2f((u16)(za1 >> 32)) + s1[64 + ul]);
            float o1 = fsig(bf2f((u16)(za1 >> 48)) + s1[96 + ul]);
            if (mc1 != 1) { c1r = f1 * c1r + i1 * g1; h1r = o1 * ftanh(c1r); }
            hb0s = f2bf(h0r); hb1s = f2bf(h1r);
            u32 nb0 = __shfl_xor((u32)hb0s, 1, 64);
            u32 nb1 = __shfl_xor((u32)hb1s, 1, 64);
            if ((ul & 1) == 0) {
                u32 pk0 = (u32)hb0s | (nb0 << 16);
                u32 pk1 = (u32)hb1s | (nb1 << 16);
                __hip_atomic_store(nx32 + b0p * 256 + (ug >> 1), pk0,
                                   __ATOMIC_RELAXED, __HIP_MEMORY_SCOPE_AGENT);
                __hip_atomic_store(nx32 + b1p * 256 + (ug >> 1), pk1,
                                   __ATOMIC_RELAXED, __HIP_MEMORY_SCOPE_AGENT);
            }
        }
        __syncthreads();   // B: implicit vmcnt(0) drains every thread's stores
        const u32 tgt = (u32)(st + 1);
        if (tid == 0)
            __hip_atomic_store(myflag, tgt, __ATOMIC_RELAXED,
                               __HIP_MEMORY_SCOPE_AGENT);
        // hseq stores: fire-and-forget, hidden under poll+stage
        hseq[hs0 + (size_t)t * 1024] = hb0s;
        hseq[hs1 + (size_t)t * 1024] = hb1s;
        // prefetch next-step z/mask (flies during the poll)
        u64 zn0 = 0, zn1 = 0; int mn0 = 0, mn1 = 0;
        {
            int stn = (st + 1 < T_) ? st + 1 : st;
            int tcn = dir ? (T_ - 1 - stn) : stn;
            wait_tb(tcn >> 7);
            zn0 = __hip_atomic_load(z64 + (size_t)(b0p * T_ + tcn) * 512 + ug,
                                    __ATOMIC_RELAXED, __HIP_MEMORY_SCOPE_AGENT);
            zn1 = __hip_atomic_load(z64 + (size_t)(b1p * T_ + tcn) * 512 + ug,
                                    __ATOMIC_RELAXED, __HIP_MEMORY_SCOPE_AGENT);
            mn0 = xmask[b0p * T_ + tcn]; mn1 = xmask[b1p * T_ + tcn];
        }
        // per-wave poll of the packed flag line (lanes<16 issue loads)
        {
            u32 v = 0xffffffffu;
            if (lane < 16)
                v = __hip_atomic_load(fbase + lane, __ATOMIC_RELAXED,
                                      __HIP_MEMORY_SCOPE_AGENT);
            while (!__all(v >= tgt)) {
                if (lane < 16)
                    v = __hip_atomic_load(fbase + lane, __ATOMIC_RELAXED,
                                          __HIP_MEMORY_SCOPE_AGENT);
            }
        }
        // stage next-parity h into LDS (coalesced agent loads, swizzled write)
        if (st + 1 < T_) {
            const u32* src = hb32 + (((st + 1) & 1) ? 8192 : 0);
            u32 tmp[16];
#pragma unroll
            for (int k = 0; k < 16; ++k)
                tmp[k] = __hip_atomic_load(src + k * 512 + tid, __ATOMIC_RELAXED,
                                           __HIP_MEMORY_SCOPE_AGENT);
#pragma unroll
            for (int k = 0; k < 16; ++k) {
                int idx = k * 512 + tid;
                int sb = (idx * 4) ^ (((idx >> 8) & 7) << 4);
                *(u32*)((char*)sh + sb) = tmp[k];
            }
        }
        za0 = zn0; za1 = zn1; mc0 = mn0; mc1 = mn1;
        __syncthreads();                               // C: sh staged by all
    }
    cst[sidx] = c0r; cst[sidx + 1] = c1r;
    hst[sidx] = h0r; hst[sidx + 1] = h1r;
}

// ---------------------------------------------------------------- heads
__global__ __launch_bounds__(256) void heads_kernel(
    const u16* __restrict__ xin,
    const float* __restrict__ Wp, const float* __restrict__ bp,
    const float* __restrict__ Wbu, const float* __restrict__ bbu,
    const float* __restrict__ Wss3, const float* __restrict__ bss3,
    const float* __restrict__ Wss8, const float* __restrict__ bss8,
    float* __restrict__ out) {
    const int r = blockIdx.x * 4 + (threadIdx.x >> 6);
    const int lane = threadIdx.x & 63;
    const u16* xr = xin + (size_t)r * 1024 + lane * 16;
    uint4 q0 = *(const uint4*)xr;
    uint4 q1 = *(const uint4*)(xr + 8);
    float xv[16];
    u32 qs[8] = { q0.x, q0.y, q0.z, q0.w, q1.x, q1.y, q1.z, q1.w };
#pragma unroll
    for (int i = 0; i < 8; ++i) {
        xv[i * 2]     = fmaxf(__uint_as_float((qs[i] & 0xffffu) << 16), 0.0f);
        xv[i * 2 + 1] = fmaxf(__uint_as_float(qs[i] & 0xffff0000u), 0.0f);
    }
    float acc[15] = {};
    const int k0 = lane * 16;
#pragma unroll
    for (int kk = 0; kk < 16; kk++) {
        float xk = xv[kk];
        int k = k0 + kk;
        acc[0] += xk * Wp[k * 2];      acc[1] += xk * Wp[k * 2 + 1];
        acc[2] += xk * Wbu[k * 2];     acc[3] += xk * Wbu[k * 2 + 1];
        acc[4] += xk * Wss3[k * 3];    acc[5] += xk * Wss3[k * 3 + 1];
        acc[6] += xk * Wss3[k * 3 + 2];
#pragma unroll
        for (int o = 0; o < 8; o++) acc[7 + o] += xk * Wss8[k * 8 + o];
    }
#pragma unroll
    for (int o = 0; o < 15; o++) {
#pragma unroll
        for (int off = 32; off; off >>= 1) acc[o] += __shfl_xor(acc[o], off, 64);
    }
    if (lane == 0) {
        float a0 = acc[0] + bp[0], a1 = acc[1] + bp[1];
        float mx = fmaxf(a0, a1);
        float e0 = expf(a0 - mx), e1 = expf(a1 - mx);
        float ssum = e0 + e1;
        out[(size_t)r * 2] = e0 / ssum;
        out[(size_t)r * 2 + 1] = e1 / ssum;
        float* ob = out + 65536;
        ob[r * 2] = acc[2] + bbu[0]; ob[r * 2 + 1] = acc[3] + bbu[1];
        float* o3 = out + 131072;
        o3[r * 3 + 0] = acc[4] + bss3[0];
        o3[r * 3 + 1] = acc[5] + bss3[1];
        o3[r * 3 + 2] = acc[6] + bss3[2];
        float* o8 = out + 229376;
#pragma unroll
        for (int o = 0; o < 8; o++) o8[r * 8 + o] = acc[7 + o] + bss8[o];
    }
}

// ---------------------------------------------------------------- launch
extern "C" void kernel_launch(void* const* d_in, const int* in_sizes, int n_in,
                              void* d_out, int out_size, void* d_ws, size_t ws_size,
                              hipStream_t stream) {
    const float* x = (const float*)d_in[0];
    const int* xmask = (const int*)d_in[1];
    const float* Wf = (const float*)d_in[2];
    const float* Uf = (const float*)d_in[3];
    const float* bfp = (const float*)d_in[4];
    const float* Wb = (const float*)d_in[5];
    const float* Ub = (const float*)d_in[6];
    const float* bbp = (const float*)d_in[7];
    const float* Wp = (const float*)d_in[8];
    const float* bp = (const float*)d_in[9];
    const float* Wbu = (const float*)d_in[10];
    const float* bbu = (const float*)d_in[11];
    const float* Wss3 = (const float*)d_in[12];
    const float* bss3 = (const float*)d_in[13];
    const float* Wss8 = (const float*)d_in[14];
    const float* bss8 = (const float*)d_in[15];

    char* wsb = (char*)d_ws;
    u16* actA = (u16*)wsb;                               // 64 MB
    u16* actB = (u16*)(wsb + (64ull << 20));             // 64 MB
    u16* wt   = (u16*)(wsb + (128ull << 20));            // 24 MB
    u16* upk  = (u16*)(wsb + (152ull << 20));            // 12 MB
    char* stb = wsb + (164ull << 20);                    // states
    u32* hbuf32 = (u32*)stb;                             // 131072 B
    float* cst = (float*)(stb + 131072);                 // 131072 B
    float* hst = (float*)(stb + 262144);                 // 131072 B
    u32* flags = (u32*)(stb + 393216);                   // 512 B (2x64 u32)
    u32* cnt   = (u32*)(stb + 393728);                   // 64 B counters
    u32* claim = (u32*)(stb + 393792);                   // 64 B claim
    const int stateFloats = (393792 + 64) / 4;

    size_t fixedB = 165ull << 20;
    u16* zf = (u16*)(wsb + fixedB);
    u16* zb = zf + (size_t)B_ * T_ * 2048;

    conv_bf16<<<dim3(8388608 / 256), 256, 0, stream>>>(x, actA);
    transpose_w<<<dim3(32, 16, 6), 256, 0, stream>>>(Wf, Wb, wt);
    pack_u<<<dim3(512, 6), 256, 0, stream>>>(Uf, Ub, upk);

    const u16* cur = actA;
    for (int l = 0; l < 3; l++) {
        u16* dst = (l & 1) ? actA : actB;
        zero_mem<<<dim3((stateFloats + 255) / 256), 256, 0, stream>>>(
            (float*)stb, stateFloats);
        u16* wtf = wt + (size_t)(l * 2 + 0) * NG * 1024;
        u16* wtb = wt + (size_t)(l * 2 + 1) * NG * 1024;
        const u16* upkl = upk + (size_t)l * 2 * 1048576;
        const float* bfl = bfp + l * NG;
        const float* bbl = bbp + l * NG;

        const u16* a_act = cur;
        const u16* a_wtf = wtf; const u16* a_wtb = wtb;
        const float* a_bf = bfl; const float* a_bb = bbl;
        u16* a_zf = zf; u16* a_zb = zb;
        const u16* a_up = upkl; const int* a_xm = xmask;
        u32* a_hb = hbuf32; float* a_cs = cst; float* a_hs = hst;
        u32* a_fl = flags; u32* a_cnt = cnt; u32* a_cl = claim;
        u16* a_hseq = dst;
        void* kargs[] = { &a_act, &a_wtf, &a_wtb, &a_bf, &a_bb, &a_zf, &a_zb,
                          &a_up, &a_xm, &a_hb, &a_cs, &a_hs, &a_fl, &a_cnt,
                          &a_cl, &a_hseq };
        hipLaunchCooperativeKernel((void*)fused_layer, dim3(NWG), dim3(512),
                                   kargs, 0, stream);
        cur = dst;
    }
    heads_kernel<<<dim3(B_ * T_ / 4), 256, 0, stream>>>(
        cur, Wp, bp, Wbu, bbu, Wss3, bss3, Wss8, bss8, (float*)d_out);
}